// Round 1
// baseline (3765.822 us; speedup 1.0000x reference)
//
#include <hip/hip_runtime.h>
#include <hip/hip_bf16.h>
#include <cstdint>

#define SEQ 2048
#define NPAD 12416      // 97*128, padded N for GEMM1
#define NTOT 12352      // qkv(8192) + z(4096) + a(32) + b(32)
#define CONV_INNER 8192

typedef __attribute__((ext_vector_type(8))) short bf16x8;
typedef __attribute__((ext_vector_type(4))) float f32x4;

__device__ __forceinline__ float b2f(unsigned short u) {
  union { unsigned int i; float f; } x; x.i = ((unsigned int)u) << 16; return x.f;
}
__device__ __forceinline__ unsigned short f2b(float f) {
  __hip_bfloat16 h = __float2bfloat16(f);
  return *reinterpret_cast<unsigned short*>(&h);
}

// ---------------- fp32 -> bf16 cast ----------------
__global__ void cast_kernel(const float* __restrict__ in, unsigned short* __restrict__ out, int n4) {
  int i = blockIdx.x * blockDim.x + threadIdx.x;
  if (i >= n4) return;
  float4 v = ((const float4*)in)[i];
  ushort4 o;
  o.x = f2b(v.x); o.y = f2b(v.y); o.z = f2b(v.z); o.w = f2b(v.w);
  ((ushort4*)out)[i] = o;
}

// ---------------- bf16 MFMA GEMM: C[m][n] = sum_k A[m][k]*B[n][k] ----------------
// 128x128 tile, BK=32, 4 waves (2x2 of 64x64), 16x16x32 MFMA.
template<bool OUT_BF16>
__global__ __launch_bounds__(256) void gemm_bt(
    const unsigned short* __restrict__ A,   // [M][K] bf16
    const unsigned short* __restrict__ Bm,  // [Nrows][K] bf16 (row-major over K)
    void* __restrict__ Cout, int K, int ldc, int nmax)
{
  __shared__ __align__(16) short lA[128 * 40];  // padded stride 40 shorts (80B)
  __shared__ __align__(16) short lB[128 * 40];
  const int tid = threadIdx.x;
  const int lane = tid & 63, wid = tid >> 6;
  const int lane16 = lane & 15, quad = lane >> 4;
  const int wm = (wid & 1) * 64, wn = (wid >> 1) * 64;
  const int m0 = blockIdx.y * 128, n0 = blockIdx.x * 128;
  const int srow = tid >> 2, sk8 = (tid & 3) * 8;   // staging: 4 threads/row, 8 elems each

  f32x4 acc[4][4];
  #pragma unroll
  for (int i = 0; i < 4; i++)
    #pragma unroll
    for (int j = 0; j < 4; j++)
      acc[i][j] = f32x4{0.f, 0.f, 0.f, 0.f};

  const short* As = (const short*)A;
  const short* Bs = (const short*)Bm;

  for (int kb = 0; kb < K; kb += 32) {
    bf16x8 ra0 = *(const bf16x8*)(As + (size_t)(m0 + srow) * K + kb + sk8);
    bf16x8 ra1 = *(const bf16x8*)(As + (size_t)(m0 + 64 + srow) * K + kb + sk8);
    bf16x8 rb0 = *(const bf16x8*)(Bs + (size_t)(n0 + srow) * K + kb + sk8);
    bf16x8 rb1 = *(const bf16x8*)(Bs + (size_t)(n0 + 64 + srow) * K + kb + sk8);
    __syncthreads();
    *(bf16x8*)&lA[srow * 40 + sk8] = ra0;
    *(bf16x8*)&lA[(64 + srow) * 40 + sk8] = ra1;
    *(bf16x8*)&lB[srow * 40 + sk8] = rb0;
    *(bf16x8*)&lB[(64 + srow) * 40 + sk8] = rb1;
    __syncthreads();
    bf16x8 af[4], bfr[4];
    #pragma unroll
    for (int t = 0; t < 4; t++) af[t]  = *(const bf16x8*)&lA[(wm + t * 16 + lane16) * 40 + quad * 8];
    #pragma unroll
    for (int t = 0; t < 4; t++) bfr[t] = *(const bf16x8*)&lB[(wn + t * 16 + lane16) * 40 + quad * 8];
    #pragma unroll
    for (int i = 0; i < 4; i++)
      #pragma unroll
      for (int j = 0; j < 4; j++)
        acc[i][j] = __builtin_amdgcn_mfma_f32_16x16x32_bf16(af[i], bfr[j], acc[i][j], 0, 0, 0);
  }

  #pragma unroll
  for (int i = 0; i < 4; i++) {
    #pragma unroll
    for (int j = 0; j < 4; j++) {
      int n = n0 + wn + j * 16 + lane16;
      if (n >= nmax) continue;
      #pragma unroll
      for (int r = 0; r < 4; r++) {
        int m = m0 + wm + i * 16 + quad * 4 + r;
        float v = acc[i][j][r];
        if (OUT_BF16) ((unsigned short*)Cout)[(size_t)m * ldc + n] = f2b(v);
        else          ((float*)Cout)[(size_t)m * ldc + n] = v;
      }
    }
  }
}

// ---------------- g -> exp(g), beta ----------------
__global__ void gebeta_kernel(const unsigned short* __restrict__ g1out,
                              const float* __restrict__ A_log, const float* __restrict__ dt_bias,
                              float* __restrict__ eg, float* __restrict__ beta)
{
  int idx = blockIdx.x * blockDim.x + threadIdx.x;  // 131072 = 4096*32
  int r = idx >> 5, n = idx & 31;
  float a = b2f(g1out[(size_t)r * NPAD + 12288 + n]) + dt_bias[n];
  float sp = (a > 20.f) ? a : log1pf(expf(a));
  float g = -expf(A_log[n]) * sp;
  eg[idx] = expf(g);
  float bv = b2f(g1out[(size_t)r * NPAD + 12320 + n]);
  beta[idx] = 1.f / (1.f + expf(-bv));
}

// ---------------- conv(4) + silu + l2norm(q,k) ----------------
__global__ __launch_bounds__(128) void conv_kernel(
    const unsigned short* __restrict__ g1out, const float* __restrict__ conv_w,
    unsigned short* __restrict__ qkv_act)
{
  const int row = blockIdx.x;            // b*SEQ + s
  const int hg  = blockIdx.y;            // 0..63 head-groups of 128 channels
  const int tid = threadIdx.x;           // 0..127
  const int c = hg * 128 + tid;
  const int s = row & (SEQ - 1);
  float acc = 0.f;
  const float* w = conv_w + (size_t)c * 4;
  #pragma unroll
  for (int j = 0; j < 4; j++) {
    int sj = s - 3 + j;
    if (sj >= 0) acc += w[j] * b2f(g1out[(size_t)(row - 3 + j) * NPAD + c]);
  }
  float sv = acc / (1.f + expf(-acc));   // silu
  float ssq = sv * sv;
  #pragma unroll
  for (int off = 32; off >= 1; off >>= 1) ssq += __shfl_xor(ssq, off, 64);
  __shared__ float r2[2];
  if ((tid & 63) == 0) r2[tid >> 6] = ssq;
  __syncthreads();
  float tot = r2[0] + r2[1];
  float scale = 1.f;
  if (hg < 32) {
    scale = rsqrtf(tot + 1e-6f);
    if (hg < 16) scale *= 0.08838834764831845f;  // 1/sqrt(128)
  }
  qkv_act[(size_t)row * CONV_INNER + c] = f2b(sv * scale);
}

// ---------------- conv_state output ----------------
__global__ void convstate_kernel(const unsigned short* __restrict__ g1out, float* __restrict__ out1)
{
  int idx = blockIdx.x * blockDim.x + threadIdx.x;  // 65536 = 2*8192*4
  int b = idx >> 15, rem = idx & 32767;
  int c = rem >> 2, j = rem & 3;
  out1[idx] = b2f(g1out[(size_t)(b * SEQ + SEQ - 4 + j) * NPAD + c]);
}

// ---------------- sequential gated delta-rule scan ----------------
// 1 block per (b,h); 256 threads; thread t owns state[v=t>>1][ (t&1)*64 .. +64 )
__global__ __launch_bounds__(256, 1) void scan_kernel(
    const unsigned short* __restrict__ qkv_act,  // [B*S][8192] bf16: qn | kn | v
    const unsigned short* __restrict__ g1out,    // [B*S][NPAD] bf16 (z at 8192..12288)
    const float* __restrict__ eg_arr, const float* __restrict__ beta_arr,
    const float* __restrict__ norm_w,
    unsigned short* __restrict__ y_out,          // [B*S][4096] bf16
    float* __restrict__ state_out)               // [B][32][128][128] fp32
{
  const int tid = threadIdx.x;
  const int b = blockIdx.x >> 5, h = blockIdx.x & 31, qh = h >> 1;
  const int vrow = tid >> 1, khalf = tid & 1, kbase = khalf << 6;
  const int lane = tid & 63, wid = tid >> 6;

  __shared__ __align__(16) float lq[2][128];
  __shared__ __align__(16) float lk[2][128];
  __shared__ __align__(16) float lv[2][128];
  __shared__ __align__(16) float lz[2][128];
  __shared__ float lsc[2][2];
  __shared__ float red[4];

  float st[64];
  #pragma unroll
  for (int i = 0; i < 64; i++) st[i] = 0.f;
  const float nw = norm_w[vrow];

  {  // prefetch s=0
    size_t row = (size_t)b * SEQ;
    const unsigned short* base = qkv_act + row * CONV_INNER;
    if (tid < 128) { lq[0][tid] = b2f(base[qh * 128 + tid]); lv[0][tid] = b2f(base[4096 + h * 128 + tid]); }
    else { int i2 = tid - 128; lk[0][i2] = b2f(base[2048 + qh * 128 + i2]);
           lz[0][i2] = b2f(g1out[row * NPAD + 8192 + h * 128 + i2]); }
    if (tid == 0) lsc[0][0] = eg_arr[row * 32 + h];
    if (tid == 1) lsc[0][1] = beta_arr[row * 32 + h];
  }
  __syncthreads();

  for (int s = 0; s < SEQ; ++s) {
    const int cur = s & 1, nxt = cur ^ 1;
    // ---- issue global prefetch for s+1 (completes during compute) ----
    float pA = 0.f, pB = 0.f, ps = 0.f;
    const bool have = (s + 1 < SEQ);
    if (have) {
      size_t row = (size_t)b * SEQ + (s + 1);
      const unsigned short* base = qkv_act + row * CONV_INNER;
      if (tid < 128) { pA = b2f(base[qh * 128 + tid]); pB = b2f(base[4096 + h * 128 + tid]); }
      else { int i2 = tid - 128; pA = b2f(base[2048 + qh * 128 + i2]);
             pB = b2f(g1out[row * NPAD + 8192 + h * 128 + i2]); }
      if (tid == 0) ps = eg_arr[row * 32 + h];
      if (tid == 1) ps = beta_arr[row * 32 + h];
    }
    // ---- compute step s ----
    const float eg = lsc[cur][0], beta = lsc[cur][1];
    float kr[64], qr[64];
    #pragma unroll
    for (int i = 0; i < 16; i++) {
      float4 k4 = *(const float4*)&lk[cur][kbase + i * 4];
      kr[4*i] = k4.x; kr[4*i+1] = k4.y; kr[4*i+2] = k4.z; kr[4*i+3] = k4.w;
      float4 q4 = *(const float4*)&lq[cur][kbase + i * 4];
      qr[4*i] = q4.x; qr[4*i+1] = q4.y; qr[4*i+2] = q4.z; qr[4*i+3] = q4.w;
    }
    float kv0 = 0.f, kv1 = 0.f, kv2 = 0.f, kv3 = 0.f;
    #pragma unroll
    for (int i = 0; i < 16; i++) {
      kv0 += st[4*i]   * kr[4*i];
      kv1 += st[4*i+1] * kr[4*i+1];
      kv2 += st[4*i+2] * kr[4*i+2];
      kv3 += st[4*i+3] * kr[4*i+3];
    }
    float kv = (kv0 + kv1) + (kv2 + kv3);
    kv += __shfl_xor(kv, 1, 64);
    const float vv = lv[cur][vrow];
    const float delta = (vv - eg * kv) * beta;   // kv_mem = eg * (S_prev . k)
    float o0 = 0.f, o1 = 0.f, o2 = 0.f, o3 = 0.f;
    #pragma unroll
    for (int i = 0; i < 16; i++) {
      st[4*i]   = st[4*i]   * eg + delta * kr[4*i];   o0 += st[4*i]   * qr[4*i];
      st[4*i+1] = st[4*i+1] * eg + delta * kr[4*i+1]; o1 += st[4*i+1] * qr[4*i+1];
      st[4*i+2] = st[4*i+2] * eg + delta * kr[4*i+2]; o2 += st[4*i+2] * qr[4*i+2];
      st[4*i+3] = st[4*i+3] * eg + delta * kr[4*i+3]; o3 += st[4*i+3] * qr[4*i+3];
    }
    float o = (o0 + o1) + (o2 + o3);
    o += __shfl_xor(o, 1, 64);
    // ---- RMSNorm over 128 v-rows (each value duplicated on thread pairs) ----
    float sq = o * o * 0.5f;
    #pragma unroll
    for (int off = 32; off >= 1; off >>= 1) sq += __shfl_xor(sq, off, 64);
    if (lane == 0) red[wid] = sq;
    __syncthreads();
    const float mean = ((red[0] + red[1]) + (red[2] + red[3])) * (1.0f / 128.0f);
    const float rinv = rsqrtf(mean + 1e-6f);
    if (khalf == 0) {
      float zv = lz[cur][vrow];
      float zg = zv * (1.f / (1.f + __expf(-zv)));    // silu(z)
      float yv = nw * (o * rinv) * zg;
      y_out[((size_t)b * SEQ + s) * 4096 + h * 128 + vrow] = f2b(yv);
    }
    // ---- write prefetch into other buffer ----
    if (have) {
      if (tid < 128) { lq[nxt][tid] = pA; lv[nxt][tid] = pB; }
      else { int i2 = tid - 128; lk[nxt][i2] = pA; lz[nxt][i2] = pB; }
      if (tid == 0) lsc[nxt][0] = ps;
      if (tid == 1) lsc[nxt][1] = ps;
    }
    __syncthreads();
  }
  // final state
  float* sp2 = state_out + (((size_t)b * 32 + h) * 128 + vrow) * 128 + kbase;
  #pragma unroll
  for (int i = 0; i < 16; i++) {
    float4 v4 = make_float4(st[4*i], st[4*i+1], st[4*i+2], st[4*i+3]);
    *(float4*)&sp2[i * 4] = v4;
  }
}

extern "C" void kernel_launch(void* const* d_in, const int* in_sizes, int n_in,
                              void* d_out, int out_size, void* d_ws, size_t ws_size,
                              hipStream_t stream)
{
  const float* hidden  = (const float*)d_in[0];
  const float* W_qkv   = (const float*)d_in[1];
  const float* W_z     = (const float*)d_in[2];
  const float* W_a     = (const float*)d_in[3];
  const float* W_b     = (const float*)d_in[4];
  const float* conv_w  = (const float*)d_in[5];
  const float* A_log   = (const float*)d_in[6];
  const float* dt_bias = (const float*)d_in[7];
  const float* norm_w  = (const float*)d_in[8];
  const float* W_out   = (const float*)d_in[9];

  char* ws = (char*)d_ws;
  unsigned short* hbf   = (unsigned short*)(ws);                 // 16.78 MB  [4096][2048] bf16
  unsigned short* Wcat  = (unsigned short*)(ws + 16777216ull);   // 50.86 MB  [12416][2048] bf16
  unsigned short* Woutb = (unsigned short*)(ws + 67633152ull);   // 16.78 MB  [2048][4096] bf16
  unsigned short* g1out = (unsigned short*)(ws + 84410368ull);   // 101.7 MB  [4096][12416] bf16
  unsigned short* qact  = (unsigned short*)(ws + 186122240ull);  // 67.1 MB   [4096][8192] bf16
  float* eg             = (float*)(ws + 253231104ull);           // 0.52 MB
  float* beta           = (float*)(ws + 253755392ull);           // 0.52 MB
  unsigned short* yout  = (unsigned short*)(ws);                 // 33.6 MB, aliases hbf+Wcat (dead after GEMM1)

  float* out0 = (float*)d_out;          // (2,2048,2048) fp32
  float* out1 = out0 + 8388608;         // conv_state (2,8192,4)
  float* out2 = out0 + 8454144;         // state (2,32,128,128)

  // casts fp32 -> bf16
  cast_kernel<<<8192,  256, 0, stream>>>(hidden, hbf, 2097152);
  cast_kernel<<<16384, 256, 0, stream>>>(W_qkv, Wcat, 4194304);
  cast_kernel<<<8192,  256, 0, stream>>>(W_z,   Wcat + 8192ull  * 2048, 2097152);
  cast_kernel<<<64,    256, 0, stream>>>(W_a,   Wcat + 12288ull * 2048, 16384);
  cast_kernel<<<64,    256, 0, stream>>>(W_b,   Wcat + 12320ull * 2048, 16384);
  cast_kernel<<<8192,  256, 0, stream>>>(W_out, Woutb, 2097152);

  // fused projection GEMM: qkv_raw | z | a | b
  gemm_bt<true><<<dim3(97, 32), 256, 0, stream>>>(hbf, Wcat, g1out, 2048, NPAD, NTOT);
  // gates
  gebeta_kernel<<<512, 256, 0, stream>>>(g1out, A_log, dt_bias, eg, beta);
  // conv + silu + l2norm
  conv_kernel<<<dim3(4096, 64), 128, 0, stream>>>(g1out, conv_w, qact);
  // conv_state output
  convstate_kernel<<<256, 256, 0, stream>>>(g1out, out1);
  // recurrent scan (+ fused RMSNorm, silu(z) gate)
  scan_kernel<<<64, 256, 0, stream>>>(qact, g1out, eg, beta, norm_w, yout, out2);
  // output projection
  gemm_bt<false><<<dim3(16, 32), 256, 0, stream>>>(yout, Woutb, out0, 4096, 2048, 2048);
}

// Round 2
// 1141.649 us; speedup vs baseline: 3.2986x; 3.2986x over previous
//
#include <hip/hip_runtime.h>
#include <hip/hip_bf16.h>
#include <cstdint>

#define SEQ 2048
#define NPAD 12416      // 97*128, padded N for GEMM1
#define NTOT 12352      // qkv(8192) + z(4096) + a(32) + b(32)
#define CONV_INNER 8192

typedef __attribute__((ext_vector_type(8))) short bf16x8;
typedef __attribute__((ext_vector_type(4))) float f32x4;

__device__ __forceinline__ float b2f(unsigned short u) {
  union { unsigned int i; float f; } x; x.i = ((unsigned int)u) << 16; return x.f;
}
__device__ __forceinline__ unsigned short f2b(float f) {
  __hip_bfloat16 h = __float2bfloat16(f);
  return *reinterpret_cast<unsigned short*>(&h);
}

// ---------------- fp32 -> bf16 cast ----------------
__global__ void cast_kernel(const float* __restrict__ in, unsigned short* __restrict__ out, int n4) {
  int i = blockIdx.x * blockDim.x + threadIdx.x;
  if (i >= n4) return;
  float4 v = ((const float4*)in)[i];
  ushort4 o;
  o.x = f2b(v.x); o.y = f2b(v.y); o.z = f2b(v.z); o.w = f2b(v.w);
  ((ushort4*)out)[i] = o;
}

// ---------------- bf16 MFMA GEMM: C[m][n] = sum_k A[m][k]*B[n][k] ----------------
template<bool OUT_BF16>
__global__ __launch_bounds__(256) void gemm_bt(
    const unsigned short* __restrict__ A,   // [M][lda] bf16
    const unsigned short* __restrict__ Bm,  // [Nrows][ldb] bf16
    void* __restrict__ Cout, int K, int lda, int ldb, int ldc, int nmax)
{
  __shared__ __align__(16) short lA[128 * 40];
  __shared__ __align__(16) short lB[128 * 40];
  const int tid = threadIdx.x;
  const int lane = tid & 63, wid = tid >> 6;
  const int lane16 = lane & 15, quad = lane >> 4;
  const int wm = (wid & 1) * 64, wn = (wid >> 1) * 64;
  const int m0 = blockIdx.y * 128, n0 = blockIdx.x * 128;
  const int srow = tid >> 2, sk8 = (tid & 3) * 8;

  f32x4 acc[4][4];
  #pragma unroll
  for (int i = 0; i < 4; i++)
    #pragma unroll
    for (int j = 0; j < 4; j++)
      acc[i][j] = f32x4{0.f, 0.f, 0.f, 0.f};

  const short* As = (const short*)A;
  const short* Bs = (const short*)Bm;

  for (int kb = 0; kb < K; kb += 32) {
    bf16x8 ra0 = *(const bf16x8*)(As + (size_t)(m0 + srow) * lda + kb + sk8);
    bf16x8 ra1 = *(const bf16x8*)(As + (size_t)(m0 + 64 + srow) * lda + kb + sk8);
    bf16x8 rb0 = *(const bf16x8*)(Bs + (size_t)(n0 + srow) * ldb + kb + sk8);
    bf16x8 rb1 = *(const bf16x8*)(Bs + (size_t)(n0 + 64 + srow) * ldb + kb + sk8);
    __syncthreads();
    *(bf16x8*)&lA[srow * 40 + sk8] = ra0;
    *(bf16x8*)&lA[(64 + srow) * 40 + sk8] = ra1;
    *(bf16x8*)&lB[srow * 40 + sk8] = rb0;
    *(bf16x8*)&lB[(64 + srow) * 40 + sk8] = rb1;
    __syncthreads();
    bf16x8 af[4], bfr[4];
    #pragma unroll
    for (int t = 0; t < 4; t++) af[t]  = *(const bf16x8*)&lA[(wm + t * 16 + lane16) * 40 + quad * 8];
    #pragma unroll
    for (int t = 0; t < 4; t++) bfr[t] = *(const bf16x8*)&lB[(wn + t * 16 + lane16) * 40 + quad * 8];
    #pragma unroll
    for (int i = 0; i < 4; i++)
      #pragma unroll
      for (int j = 0; j < 4; j++)
        acc[i][j] = __builtin_amdgcn_mfma_f32_16x16x32_bf16(af[i], bfr[j], acc[i][j], 0, 0, 0);
  }

  #pragma unroll
  for (int i = 0; i < 4; i++) {
    #pragma unroll
    for (int j = 0; j < 4; j++) {
      int n = n0 + wn + j * 16 + lane16;
      if (n >= nmax) continue;
      #pragma unroll
      for (int r = 0; r < 4; r++) {
        int m = m0 + wm + i * 16 + quad * 4 + r;
        float v = acc[i][j][r];
        if (OUT_BF16) ((unsigned short*)Cout)[(size_t)m * ldc + n] = f2b(v);
        else          ((float*)Cout)[(size_t)m * ldc + n] = v;
      }
    }
  }
}

// ---------------- gates: g (log decay) and beta ----------------
__global__ void gebeta_kernel(const unsigned short* __restrict__ g1out,
                              const float* __restrict__ A_log, const float* __restrict__ dt_bias,
                              float* __restrict__ g_out, float* __restrict__ beta)
{
  int idx = blockIdx.x * blockDim.x + threadIdx.x;  // 131072 = 4096*32
  int r = idx >> 5, n = idx & 31;
  float a = b2f(g1out[(size_t)r * NPAD + 12288 + n]) + dt_bias[n];
  float sp = (a > 20.f) ? a : log1pf(expf(a));
  g_out[idx] = -expf(A_log[n]) * sp;
  float bv = b2f(g1out[(size_t)r * NPAD + 12320 + n]);
  beta[idx] = 1.f / (1.f + expf(-bv));
}

// ---------------- conv(4) + silu + l2norm(q,k) ----------------
__global__ __launch_bounds__(128) void conv_kernel(
    const unsigned short* __restrict__ g1out, const float* __restrict__ conv_w,
    unsigned short* __restrict__ qkv_act)
{
  const int row = blockIdx.x;
  const int hg  = blockIdx.y;
  const int tid = threadIdx.x;
  const int c = hg * 128 + tid;
  const int s = row & (SEQ - 1);
  float acc = 0.f;
  const float* w = conv_w + (size_t)c * 4;
  #pragma unroll
  for (int j = 0; j < 4; j++) {
    int sj = s - 3 + j;
    if (sj >= 0) acc += w[j] * b2f(g1out[(size_t)(row - 3 + j) * NPAD + c]);
  }
  float sv = acc / (1.f + expf(-acc));
  float ssq = sv * sv;
  #pragma unroll
  for (int off = 32; off >= 1; off >>= 1) ssq += __shfl_xor(ssq, off, 64);
  __shared__ float r2[2];
  if ((tid & 63) == 0) r2[tid >> 6] = ssq;
  __syncthreads();
  float tot = r2[0] + r2[1];
  float scale = 1.f;
  if (hg < 32) {
    scale = rsqrtf(tot + 1e-6f);
    if (hg < 16) scale *= 0.08838834764831845f;
  }
  qkv_act[(size_t)row * CONV_INNER + c] = f2b(sv * scale);
}

// ---------------- conv_state output ----------------
__global__ void convstate_kernel(const unsigned short* __restrict__ g1out, float* __restrict__ out1)
{
  int idx = blockIdx.x * blockDim.x + threadIdx.x;
  int b = idx >> 15, rem = idx & 32767;
  int c = rem >> 2, j = rem & 3;
  out1[idx] = b2f(g1out[(size_t)(b * SEQ + SEQ - 4 + j) * NPAD + c]);
}

// ================= PASS 1: chunk-local W,U (UT transform) =================
// grid 2048 = (b, h, chunk); block 256
__global__ __launch_bounds__(256, 2) void chunk_prep(
    const unsigned short* __restrict__ qact,
    const float* __restrict__ g_arr, const float* __restrict__ beta_arr,
    unsigned short* __restrict__ W_all, unsigned short* __restrict__ U_all)
{
  __shared__ __align__(16) char smem[73472];
  short* sKn = (short*)smem;                  // 64 x stride152 (19456 B); Vt (128x72) aliases
  short* sVt = (short*)smem;
  short* sKt = (short*)(smem + 19456);        // 128 x 72 (18432 B)
  float* sA  = (float*)(smem + 37888);        // 64 x 68 fp32 (17408 B); Tb aliases
  short* sTb = (short*)(smem + 37888);        // 64 x 72 bf16
  float* sT  = (float*)(smem + 55296);        // 64 x 68 fp32 (17408 B)
  float* sl  = (float*)(smem + 72704);
  float* sel = (float*)(smem + 72960);
  float* sbb = (float*)(smem + 73216);

  const int tid = threadIdx.x, lane = tid & 63, wid = tid >> 6;
  const int lane16 = lane & 15, quad = lane >> 4;
  const int cid = blockIdx.x;
  const int ch = cid & 31, h = (cid >> 5) & 31, b = cid >> 10;
  const int qh = h >> 1;
  const int row0 = b * SEQ + ch * 64;

  // per-wave redundant: g cumsum over 64 rows (lane = row)
  float gv = g_arr[(size_t)(row0 + lane) * 32 + h];
  float bb = beta_arr[(size_t)(row0 + lane) * 32 + h];
  float l = gv;
  #pragma unroll
  for (int off = 1; off < 64; off <<= 1) {
    float p = __shfl_up(l, off, 64);
    if (lane >= off) l += p;
  }
  float el = expf(l);
  if (wid == 0) { sl[lane] = l; sel[lane] = el; sbb[lane] = bb; }

  // stage Kn (coalesced)
  {
    int j = tid >> 2, kc = (tid & 3) * 32;
    const unsigned short* src = qact + (size_t)(row0 + j) * CONV_INNER + 2048 + qh * 128 + kc;
    #pragma unroll
    for (int u = 0; u < 4; u++) {
      bf16x8 r = *(const bf16x8*)(src + u * 8);
      *(bf16x8*)&sKn[j * 152 + kc + u * 8] = r;
    }
  }
  // stage Kt scaled by beta_j * el_j (lane-row pattern; this lane's row = lane)
  {
    const unsigned short* src = qact + (size_t)(row0 + lane) * CONV_INNER + 2048 + qh * 128 + wid * 32;
    float cj = bb * el;
    #pragma unroll
    for (int u = 0; u < 4; u++) {
      bf16x8 r = *(const bf16x8*)(src + u * 8);
      #pragma unroll
      for (int e = 0; e < 8; e++)
        sKt[(wid * 32 + u * 8 + e) * 72 + lane] = (short)f2b(b2f((unsigned short)r[e]) * cj);
    }
  }
  __syncthreads();

  // KK^T -> A (masked, scaled)
  {
    f32x4 accA[4];
    #pragma unroll
    for (int t = 0; t < 4; t++) accA[t] = f32x4{0.f, 0.f, 0.f, 0.f};
    #pragma unroll
    for (int ks = 0; ks < 4; ks++) {
      bf16x8 a = *(const bf16x8*)&sKn[(wid * 16 + lane16) * 152 + ks * 32 + quad * 8];
      #pragma unroll
      for (int jt = 0; jt < 4; jt++) {
        bf16x8 bfr = *(const bf16x8*)&sKn[(jt * 16 + lane16) * 152 + ks * 32 + quad * 8];
        accA[jt] = __builtin_amdgcn_mfma_f32_16x16x32_bf16(a, bfr, accA[jt], 0, 0, 0);
      }
    }
    #pragma unroll
    for (int jt = 0; jt < 4; jt++) {
      int j = jt * 16 + lane16;
      float lj = sl[j];
      #pragma unroll
      for (int r = 0; r < 4; r++) {
        int i = wid * 16 + quad * 4 + r;
        float v = (j < i) ? sbb[i] * expf(sl[i] - lj) * accA[jt][r] : 0.f;
        sA[i * 68 + j] = v;
      }
    }
  }
  __syncthreads();

  // stage Vt (over Kn) scaled by beta_j
  {
    const unsigned short* src = qact + (size_t)(row0 + lane) * CONV_INNER + 4096 + h * 128 + wid * 32;
    #pragma unroll
    for (int u = 0; u < 4; u++) {
      bf16x8 r = *(const bf16x8*)(src + u * 8);
      #pragma unroll
      for (int e = 0; e < 8; e++)
        sVt[(wid * 32 + u * 8 + e) * 72 + lane] = (short)f2b(b2f((unsigned short)r[e]) * bb);
    }
  }
  __syncthreads();

  // invert (I + A): blocked forward substitution
  if (wid == 0 && lane < 32) {
    int c = lane;
    float treg[32];
    treg[0] = (c == 0) ? 1.f : 0.f;
    #pragma unroll
    for (int i = 1; i < 32; i++) {
      float s = 0.f;
      #pragma unroll
      for (int j = 0; j < i; j++) s += sA[i * 68 + j] * treg[j];
      treg[i] = ((i == c) ? 1.f : 0.f) - s;
    }
    #pragma unroll
    for (int i = 0; i < 32; i++) sT[i * 68 + c] = treg[i];
  } else if (wid == 1 && lane < 32) {
    int c = lane;
    float treg[32];
    treg[0] = (c == 0) ? 1.f : 0.f;
    #pragma unroll
    for (int i = 1; i < 32; i++) {
      float s = 0.f;
      #pragma unroll
      for (int j = 0; j < i; j++) s += sA[(32 + i) * 68 + 32 + j] * treg[j];
      treg[i] = ((i == c) ? 1.f : 0.f) - s;
    }
    #pragma unroll
    for (int i = 0; i < 32; i++) sT[(32 + i) * 68 + 32 + c] = treg[i];
  } else if (wid == 2) {
    for (int e = lane; e < 1024; e += 64) sT[(e >> 5) * 68 + 32 + (e & 31)] = 0.f;
  }
  __syncthreads();

  // X = A21 * T1 -> sA rows 0..31
  {
    int i = tid & 31, c0 = (tid >> 5) * 4;
    float x[4] = {0.f, 0.f, 0.f, 0.f};
    #pragma unroll
    for (int j = 0; j < 32; j++) {
      float a = sA[(32 + i) * 68 + j];
      #pragma unroll
      for (int cc = 0; cc < 4; cc++) x[cc] += a * sT[j * 68 + c0 + cc];
    }
    #pragma unroll
    for (int cc = 0; cc < 4; cc++) sA[i * 68 + c0 + cc] = x[cc];
  }
  __syncthreads();
  // T21 = -T2 * X
  {
    int i = tid & 31, c0 = (tid >> 5) * 4;
    float x[4] = {0.f, 0.f, 0.f, 0.f};
    #pragma unroll
    for (int j = 0; j < 32; j++) {
      float t2 = sT[(32 + i) * 68 + 32 + j];
      #pragma unroll
      for (int cc = 0; cc < 4; cc++) x[cc] += t2 * sA[j * 68 + c0 + cc];
    }
    #pragma unroll
    for (int cc = 0; cc < 4; cc++) sT[(32 + i) * 68 + c0 + cc] = -x[cc];
  }
  __syncthreads();
  // Tb = bf16(T)  (aliases sA; all sA reads done)
  #pragma unroll
  for (int ii = 0; ii < 16; ii++) {
    int e = tid + 256 * ii;
    int r = e >> 6, cc = e & 63;
    sTb[r * 72 + cc] = (short)f2b(sT[r * 68 + cc]);
  }
  __syncthreads();

  // W = Tb x Kt ; U = Tb x Vt  (contraction over j=64)
  {
    f32x4 accW[8], accU[8];
    #pragma unroll
    for (int nt = 0; nt < 8; nt++) { accW[nt] = f32x4{0.f,0.f,0.f,0.f}; accU[nt] = f32x4{0.f,0.f,0.f,0.f}; }
    bf16x8 ta[2];
    #pragma unroll
    for (int ks = 0; ks < 2; ks++)
      ta[ks] = *(const bf16x8*)&sTb[(wid * 16 + lane16) * 72 + ks * 32 + quad * 8];
    #pragma unroll
    for (int nt = 0; nt < 8; nt++) {
      #pragma unroll
      for (int ks = 0; ks < 2; ks++) {
        bf16x8 bk = *(const bf16x8*)&sKt[(nt * 16 + lane16) * 72 + ks * 32 + quad * 8];
        accW[nt] = __builtin_amdgcn_mfma_f32_16x16x32_bf16(ta[ks], bk, accW[nt], 0, 0, 0);
        bf16x8 bv = *(const bf16x8*)&sVt[(nt * 16 + lane16) * 72 + ks * 32 + quad * 8];
        accU[nt] = __builtin_amdgcn_mfma_f32_16x16x32_bf16(ta[ks], bv, accU[nt], 0, 0, 0);
      }
    }
    unsigned short* Wg = W_all + (size_t)cid * 8192;
    unsigned short* Ug = U_all + (size_t)cid * 8192;
    #pragma unroll
    for (int nt = 0; nt < 8; nt++)
      #pragma unroll
      for (int r = 0; r < 4; r++) {
        int i = wid * 16 + quad * 4 + r, k = nt * 16 + lane16;
        Wg[i * 128 + k] = f2b(accW[nt][r]);
        Ug[i * 128 + k] = f2b(accU[nt][r]);
      }
  }
}

// ================= PASS 2: sequential chunk scan with MFMA =================
// grid 64 = (b,h); block 256
__global__ __launch_bounds__(256, 1) void chunk_scan(
    const unsigned short* __restrict__ qact,
    unsigned short* __restrict__ g1out,     // z read; y written into cols [0,4096)
    const float* __restrict__ g_arr,
    const float* __restrict__ norm_w,
    const unsigned short* __restrict__ W_all, const unsigned short* __restrict__ U_all,
    float* __restrict__ state_out)
{
  __shared__ __align__(16) char smem[142336];
  short* sS  = (short*)smem;                  // 128 x 136 (34816)
  short* sQ  = (short*)(smem + 34816);        // 64 x 136 (17408)
  short* sKn = (short*)(smem + 52224);        // 64 x 136; sM (64x72) aliases
  short* sM  = (short*)(smem + 52224);
  short* sW  = (short*)(smem + 69632);        // 64 x 136
  short* sDt = (short*)(smem + 87040);        // 128 x 72 (18432)
  short* sK2 = (short*)(smem + 105472);       // 128 x 72 (18432)
  short* sZ  = (short*)(smem + 123904);       // 64 x 136
  float* sl  = (float*)(smem + 141312);
  float* sel = (float*)(smem + 141568);
  float* snw = (float*)(smem + 141824);       // 128 f32

  const int tid = threadIdx.x, lane = tid & 63, wid = tid >> 6;
  const int lane16 = lane & 15, quad = lane >> 4;
  const int bh = blockIdx.x;
  const int h = bh & 31, b = bh >> 5, qh = h >> 1;

  for (int e = tid; e < 8704; e += 256) ((unsigned int*)sS)[e] = 0u;
  if (tid < 128) snw[tid] = norm_w[tid];
  float Sreg[2][8][4];
  #pragma unroll
  for (int vt2 = 0; vt2 < 2; vt2++)
    #pragma unroll
    for (int kt = 0; kt < 8; kt++)
      #pragma unroll
      for (int r = 0; r < 4; r++) Sreg[vt2][kt][r] = 0.f;

  for (int ch = 0; ch < 32; ch++) {
    const int cid = (bh << 5) + ch;
    const int row0 = b * SEQ + ch * 64;

    // g cumsum (redundant per wave; lane = row in chunk)
    float gv = g_arr[(size_t)(row0 + lane) * 32 + h];
    float l = gv;
    #pragma unroll
    for (int off = 1; off < 64; off <<= 1) {
      float p = __shfl_up(l, off, 64);
      if (lane >= off) l += p;
    }
    float lC = __shfl(l, 63, 64);
    float elC = expf(lC);
    if (wid == 0) { sl[lane] = l; sel[lane] = expf(l); }

    // coalesced staging
    {
      int j4 = tid >> 2, kc = (tid & 3) * 32;
      const unsigned short* sq = qact + (size_t)(row0 + j4) * CONV_INNER + qh * 128 + kc;
      const unsigned short* sk = sq + 2048;
      const unsigned short* sw = W_all + (size_t)cid * 8192 + j4 * 128 + kc;
      const unsigned short* sz = g1out + (size_t)(row0 + j4) * NPAD + 8192 + h * 128 + kc;
      #pragma unroll
      for (int u = 0; u < 4; u++) *(bf16x8*)&sQ[j4 * 136 + kc + u * 8] = *(const bf16x8*)(sq + u * 8);
      #pragma unroll
      for (int u = 0; u < 4; u++) *(bf16x8*)&sKn[j4 * 136 + kc + u * 8] = *(const bf16x8*)(sk + u * 8);
      #pragma unroll
      for (int u = 0; u < 4; u++) {
        bf16x8 rw = *(const bf16x8*)(sw + u * 8);
        #pragma unroll
        for (int e = 0; e < 8; e++) rw[e] = (short)(rw[e] ^ (short)0x8000);   // -W
        *(bf16x8*)&sW[j4 * 136 + kc + u * 8] = rw;
      }
      #pragma unroll
      for (int u = 0; u < 4; u++) *(bf16x8*)&sZ[j4 * 136 + kc + u * 8] = *(const bf16x8*)(sz + u * 8);
    }
    // K2t = exp(lC - l_j) * k_j, transposed (lane-row pattern)
    {
      const unsigned short* src = qact + (size_t)(row0 + lane) * CONV_INNER + 2048 + qh * 128 + wid * 32;
      float s2 = expf(lC - l);
      #pragma unroll
      for (int u = 0; u < 4; u++) {
        bf16x8 r = *(const bf16x8*)(src + u * 8);
        #pragma unroll
        for (int e = 0; e < 8; e++)
          sK2[(wid * 32 + u * 8 + e) * 72 + lane] = (short)f2b(b2f((unsigned short)r[e]) * s2);
      }
    }
    // U fragments from global (overlaps with LDS waits)
    float uv[8][4];
    {
      const unsigned short* Ug = U_all + (size_t)cid * 8192;
      #pragma unroll
      for (int nt = 0; nt < 8; nt++)
        #pragma unroll
        for (int r = 0; r < 4; r++)
          uv[nt][r] = b2f(Ug[(wid * 16 + quad * 4 + r) * 128 + nt * 16 + lane16]);
    }
    __syncthreads();   // B1

    // delta = U - W S0^T   (acc = (-W)*S, then + U at write)
    {
      f32x4 aD[8];
      #pragma unroll
      for (int nt = 0; nt < 8; nt++) aD[nt] = f32x4{0.f,0.f,0.f,0.f};
      #pragma unroll
      for (int ks = 0; ks < 4; ks++) {
        bf16x8 a = *(const bf16x8*)&sW[(wid * 16 + lane16) * 136 + ks * 32 + quad * 8];
        #pragma unroll
        for (int nt = 0; nt < 8; nt++) {
          bf16x8 bfr = *(const bf16x8*)&sS[(nt * 16 + lane16) * 136 + ks * 32 + quad * 8];
          aD[nt] = __builtin_amdgcn_mfma_f32_16x16x32_bf16(a, bfr, aD[nt], 0, 0, 0);
        }
      }
      #pragma unroll
      for (int nt = 0; nt < 8; nt++)
        #pragma unroll
        for (int r = 0; r < 4; r++)
          sDt[(nt * 16 + lane16) * 72 + wid * 16 + quad * 4 + r] = (short)f2b(aD[nt][r] + uv[nt][r]);
    }

    // QK^T (before barrier so Kn reads complete wave-locally; cross-wave via B2)
    f32x4 aM[4];
    #pragma unroll
    for (int jt = 0; jt < 4; jt++) aM[jt] = f32x4{0.f,0.f,0.f,0.f};
    #pragma unroll
    for (int ks = 0; ks < 4; ks++) {
      bf16x8 a = *(const bf16x8*)&sQ[(wid * 16 + lane16) * 136 + ks * 32 + quad * 8];
      #pragma unroll
      for (int jt = 0; jt < 4; jt++) {
        bf16x8 bfr = *(const bf16x8*)&sKn[(jt * 16 + lane16) * 136 + ks * 32 + quad * 8];
        aM[jt] = __builtin_amdgcn_mfma_f32_16x16x32_bf16(a, bfr, aM[jt], 0, 0, 0);
      }
    }
    __syncthreads();   // B2: delta^T visible; Kn reads done everywhere

    // write M = tril(exp(l_i-l_j) * q_i.k_j)  (aliases Kn)
    #pragma unroll
    for (int jt = 0; jt < 4; jt++) {
      int j = jt * 16 + lane16;
      float lj = sl[j];
      #pragma unroll
      for (int r = 0; r < 4; r++) {
        int i = wid * 16 + quad * 4 + r;
        float m = (j <= i) ? expf(sl[i] - lj) * aM[jt][r] : 0.f;
        sM[i * 72 + j] = (short)f2b(m);
      }
    }
    // o = el_i * Q S0^T ...
    f32x4 aO[8];
    #pragma unroll
    for (int nt = 0; nt < 8; nt++) aO[nt] = f32x4{0.f,0.f,0.f,0.f};
    #pragma unroll
    for (int ks = 0; ks < 4; ks++) {
      bf16x8 a = *(const bf16x8*)&sQ[(wid * 16 + lane16) * 136 + ks * 32 + quad * 8];
      #pragma unroll
      for (int nt = 0; nt < 8; nt++) {
        bf16x8 bfr = *(const bf16x8*)&sS[(nt * 16 + lane16) * 136 + ks * 32 + quad * 8];
        aO[nt] = __builtin_amdgcn_mfma_f32_16x16x32_bf16(a, bfr, aO[nt], 0, 0, 0);
      }
    }
    #pragma unroll
    for (int r = 0; r < 4; r++) {
      float eli = sel[wid * 16 + quad * 4 + r];
      #pragma unroll
      for (int nt = 0; nt < 8; nt++) aO[nt][r] *= eli;
    }
    __syncthreads();   // B3: M visible

    // ... + M * delta
    #pragma unroll
    for (int ks = 0; ks < 2; ks++) {
      bf16x8 a = *(const bf16x8*)&sM[(wid * 16 + lane16) * 72 + ks * 32 + quad * 8];
      #pragma unroll
      for (int nt = 0; nt < 8; nt++) {
        bf16x8 bfr = *(const bf16x8*)&sDt[(nt * 16 + lane16) * 72 + ks * 32 + quad * 8];
        aO[nt] = __builtin_amdgcn_mfma_f32_16x16x32_bf16(a, bfr, aO[nt], 0, 0, 0);
      }
    }
    // epilogue: RMSNorm + silu(z) gate + y store
    #pragma unroll
    for (int r = 0; r < 4; r++) {
      float ss = 0.f;
      #pragma unroll
      for (int nt = 0; nt < 8; nt++) ss += aO[nt][r] * aO[nt][r];
      ss += __shfl_xor(ss, 1, 64);
      ss += __shfl_xor(ss, 2, 64);
      ss += __shfl_xor(ss, 4, 64);
      ss += __shfl_xor(ss, 8, 64);
      float rinv = rsqrtf(ss * (1.f / 128.f) + 1e-6f);
      int i = wid * 16 + quad * 4 + r;
      size_t grow = (size_t)(row0 + i) * NPAD + h * 128;
      #pragma unroll
      for (int nt = 0; nt < 8; nt++) {
        int v = nt * 16 + lane16;
        float zv = b2f((unsigned short)sZ[i * 136 + v]);
        float zg = zv / (1.f + __expf(-zv));
        float y = snw[v] * (aO[nt][r] * rinv) * zg;
        g1out[grow + v] = f2b(y);
      }
    }
    // state update: S = elC*S + K2^T delta
    #pragma unroll
    for (int vt2 = 0; vt2 < 2; vt2++) {
      f32x4 aS[8];
      #pragma unroll
      for (int kt = 0; kt < 8; kt++) aS[kt] = f32x4{0.f,0.f,0.f,0.f};
      #pragma unroll
      for (int ks = 0; ks < 2; ks++) {
        bf16x8 a = *(const bf16x8*)&sDt[((wid * 2 + vt2) * 16 + lane16) * 72 + ks * 32 + quad * 8];
        #pragma unroll
        for (int kt = 0; kt < 8; kt++) {
          bf16x8 bfr = *(const bf16x8*)&sK2[(kt * 16 + lane16) * 72 + ks * 32 + quad * 8];
          aS[kt] = __builtin_amdgcn_mfma_f32_16x16x32_bf16(a, bfr, aS[kt], 0, 0, 0);
        }
      }
      #pragma unroll
      for (int kt = 0; kt < 8; kt++)
        #pragma unroll
        for (int r = 0; r < 4; r++)
          Sreg[vt2][kt][r] = elC * Sreg[vt2][kt][r] + aS[kt][r];
    }
    __syncthreads();   // B4: all S/staging reads of this chunk done
    #pragma unroll
    for (int vt2 = 0; vt2 < 2; vt2++)
      #pragma unroll
      for (int kt = 0; kt < 8; kt++)
        #pragma unroll
        for (int r = 0; r < 4; r++)
          sS[((wid * 2 + vt2) * 16 + quad * 4 + r) * 136 + kt * 16 + lane16] = (short)f2b(Sreg[vt2][kt][r]);
    __syncthreads();   // B5: new S visible
  }

  // final state
  float* so = state_out + (size_t)bh * 16384;
  #pragma unroll
  for (int vt2 = 0; vt2 < 2; vt2++)
    #pragma unroll
    for (int kt = 0; kt < 8; kt++)
      #pragma unroll
      for (int r = 0; r < 4; r++)
        so[((wid * 2 + vt2) * 16 + quad * 4 + r) * 128 + kt * 16 + lane16] = Sreg[vt2][kt][r];
}

extern "C" void kernel_launch(void* const* d_in, const int* in_sizes, int n_in,
                              void* d_out, int out_size, void* d_ws, size_t ws_size,
                              hipStream_t stream)
{
  const float* hidden  = (const float*)d_in[0];
  const float* W_qkv   = (const float*)d_in[1];
  const float* W_z     = (const float*)d_in[2];
  const float* W_a     = (const float*)d_in[3];
  const float* W_b     = (const float*)d_in[4];
  const float* conv_w  = (const float*)d_in[5];
  const float* A_log   = (const float*)d_in[6];
  const float* dt_bias = (const float*)d_in[7];
  const float* norm_w  = (const float*)d_in[8];
  const float* W_out   = (const float*)d_in[9];

  char* ws = (char*)d_ws;
  unsigned short* hbf   = (unsigned short*)(ws);                 // [4096][2048] bf16
  unsigned short* Wcat  = (unsigned short*)(ws + 16777216ull);   // [12416][2048] bf16
  unsigned short* Woutb = (unsigned short*)(ws + 67633152ull);   // [2048][4096] bf16
  unsigned short* g1out = (unsigned short*)(ws + 84410368ull);   // [4096][12416] bf16
  unsigned short* qact  = (unsigned short*)(ws + 186122240ull);  // [4096][8192] bf16
  float* g_arr          = (float*)(ws + 253231104ull);           // [4096][32]
  float* beta           = (float*)(ws + 253755392ull);           // [4096][32]
  unsigned short* W_all = (unsigned short*)(ws);                 // [2048][64][128] bf16 (aliases hbf, dead after GEMM1)
  unsigned short* U_all = (unsigned short*)(ws + 33554432ull);   // [2048][64][128] bf16 (aliases Wcat tail)

  float* out0 = (float*)d_out;          // (2,2048,2048) fp32
  float* out1 = out0 + 8388608;         // conv_state (2,8192,4)
  float* out2 = out0 + 8454144;         // state (2,32,128,128)

  cast_kernel<<<8192,  256, 0, stream>>>(hidden, hbf, 2097152);
  cast_kernel<<<16384, 256, 0, stream>>>(W_qkv, Wcat, 4194304);
  cast_kernel<<<8192,  256, 0, stream>>>(W_z,   Wcat + 8192ull  * 2048, 2097152);
  cast_kernel<<<64,    256, 0, stream>>>(W_a,   Wcat + 12288ull * 2048, 16384);
  cast_kernel<<<64,    256, 0, stream>>>(W_b,   Wcat + 12320ull * 2048, 16384);
  cast_kernel<<<8192,  256, 0, stream>>>(W_out, Woutb, 2097152);

  gemm_bt<true><<<dim3(97, 32), 256, 0, stream>>>(hbf, Wcat, g1out, 2048, 2048, 2048, NPAD, NTOT);
  gebeta_kernel<<<512, 256, 0, stream>>>(g1out, A_log, dt_bias, g_arr, beta);
  conv_kernel<<<dim3(4096, 64), 128, 0, stream>>>(g1out, conv_w, qact);
  convstate_kernel<<<256, 256, 0, stream>>>(g1out, out1);

  chunk_prep<<<2048, 256, 0, stream>>>(qact, g_arr, beta, W_all, U_all);
  chunk_scan<<<64, 256, 0, stream>>>(qact, g1out, g_arr, norm_w, W_all, U_all, out2);

  gemm_bt<false><<<dim3(16, 32), 256, 0, stream>>>(g1out, Woutb, out0, 4096, NPAD, 4096, 2048, 2048);
}

// Round 3
// 1118.908 us; speedup vs baseline: 3.3656x; 1.0203x over previous
//
#include <hip/hip_runtime.h>
#include <hip/hip_bf16.h>
#include <cstdint>

#define SEQ 2048
#define NPAD 12416      // 97*128, padded N for GEMM1
#define NTOT 12352      // qkv(8192) + z(4096) + a(32) + b(32)
#define CONV_INNER 8192

typedef __attribute__((ext_vector_type(8))) short bf16x8;
typedef __attribute__((ext_vector_type(4))) float f32x4;

__device__ __forceinline__ float b2f(unsigned short u) {
  union { unsigned int i; float f; } x; x.i = ((unsigned int)u) << 16; return x.f;
}
__device__ __forceinline__ unsigned short f2b(float f) {
  __hip_bfloat16 h = __float2bfloat16(f);
  return *reinterpret_cast<unsigned short*>(&h);
}
__device__ __forceinline__ void load_lds16(const short* g, short* l) {
  __builtin_amdgcn_global_load_lds(
      (__attribute__((address_space(1))) void*)(g),
      (__attribute__((address_space(3))) void*)(l), 16, 0, 0);
}

// ---------------- fp32 -> bf16 cast ----------------
__global__ void cast_kernel(const float* __restrict__ in, unsigned short* __restrict__ out, int n4) {
  int i = blockIdx.x * blockDim.x + threadIdx.x;
  if (i >= n4) return;
  float4 v = ((const float4*)in)[i];
  ushort4 o;
  o.x = f2b(v.x); o.y = f2b(v.y); o.z = f2b(v.z); o.w = f2b(v.w);
  ((ushort4*)out)[i] = o;
}

// ---------------- bf16 MFMA GEMM (m97 structure): C[m][n] = sum_k A[m][k]*B[n][k] ----
template<bool OUT_BF16>
__global__ __launch_bounds__(256) void gemm_bt(
    const unsigned short* __restrict__ A,   // [M][lda] bf16
    const unsigned short* __restrict__ Bm,  // [Nrows][ldb] bf16
    void* __restrict__ Cout, int K, int lda, int ldb, int ldc, int nmax)
{
  __shared__ __align__(16) short lA[128 * 32];   // unpadded: global_load_lds layout
  __shared__ __align__(16) short lB[128 * 32];
  const int tid = threadIdx.x;
  const int lane = tid & 63, wid = tid >> 6;
  const int lane16 = lane & 15, quad = lane >> 4;
  const int wm = (wid & 1) * 64, wn = (wid >> 1) * 64;
  const int m0 = blockIdx.y * 128, n0 = blockIdx.x * 128;
  const int srow = wid * 16 + (lane >> 2);   // global staging row within tile
  const int scol = (lane & 3) * 8;

  f32x4 acc[4][4];
  #pragma unroll
  for (int i = 0; i < 4; i++)
    #pragma unroll
    for (int j = 0; j < 4; j++)
      acc[i][j] = f32x4{0.f, 0.f, 0.f, 0.f};

  const short* As = (const short*)A;
  const short* Bs = (const short*)Bm;
  // wave-uniform LDS bases (lane scatter is implicit: base + lane*16B)
  short* lA0 = &lA[(wid * 16) * 32];
  short* lA1 = &lA[(64 + wid * 16) * 32];
  short* lB0 = &lB[(wid * 16) * 32];
  short* lB1 = &lB[(64 + wid * 16) * 32];
  const short* ga0 = As + (size_t)(m0 + srow) * lda + scol;
  const short* ga1 = As + (size_t)(m0 + 64 + srow) * lda + scol;
  const short* gb0 = Bs + (size_t)(n0 + srow) * ldb + scol;
  const short* gb1 = Bs + (size_t)(n0 + 64 + srow) * ldb + scol;

  for (int kb = 0; kb < K; kb += 32) {
    load_lds16(ga0 + kb, lA0);
    load_lds16(ga1 + kb, lA1);
    load_lds16(gb0 + kb, lB0);
    load_lds16(gb1 + kb, lB1);
    __syncthreads();   // drains vmcnt -> LDS tiles complete
    bf16x8 af[4], bfr[4];
    #pragma unroll
    for (int t = 0; t < 4; t++) af[t]  = *(const bf16x8*)&lA[(wm + t * 16 + lane16) * 32 + quad * 8];
    #pragma unroll
    for (int t = 0; t < 4; t++) bfr[t] = *(const bf16x8*)&lB[(wn + t * 16 + lane16) * 32 + quad * 8];
    #pragma unroll
    for (int i = 0; i < 4; i++)
      #pragma unroll
      for (int j = 0; j < 4; j++)
        acc[i][j] = __builtin_amdgcn_mfma_f32_16x16x32_bf16(af[i], bfr[j], acc[i][j], 0, 0, 0);
    __syncthreads();   // all reads done before next overwrite
  }

  #pragma unroll
  for (int i = 0; i < 4; i++) {
    #pragma unroll
    for (int j = 0; j < 4; j++) {
      int n = n0 + wn + j * 16 + lane16;
      if (n >= nmax) continue;
      #pragma unroll
      for (int r = 0; r < 4; r++) {
        int m = m0 + wm + i * 16 + quad * 4 + r;
        float v = acc[i][j][r];
        if (OUT_BF16) ((unsigned short*)Cout)[(size_t)m * ldc + n] = f2b(v);
        else          ((float*)Cout)[(size_t)m * ldc + n] = v;
      }
    }
  }
}

// ---------------- gates: g (log decay) and beta ----------------
__global__ void gebeta_kernel(const unsigned short* __restrict__ g1out,
                              const float* __restrict__ A_log, const float* __restrict__ dt_bias,
                              float* __restrict__ g_out, float* __restrict__ beta)
{
  int idx = blockIdx.x * blockDim.x + threadIdx.x;  // 131072 = 4096*32
  int r = idx >> 5, n = idx & 31;
  float a = b2f(g1out[(size_t)r * NPAD + 12288 + n]) + dt_bias[n];
  float sp = (a > 20.f) ? a : log1pf(expf(a));
  g_out[idx] = -expf(A_log[n]) * sp;
  float bv = b2f(g1out[(size_t)r * NPAD + 12320 + n]);
  beta[idx] = 1.f / (1.f + expf(-bv));
}

// ---------------- conv(4) + silu + l2norm(q,k), 8 ch/thread ----------------
__global__ __launch_bounds__(128) void conv_kernel(
    const unsigned short* __restrict__ g1out, const float* __restrict__ conv_w,
    unsigned short* __restrict__ qkv_act)
{
  const int row = blockIdx.x;            // b*SEQ + s
  const int hg  = blockIdx.y;            // 0..7 (1024 channels each)
  const int tid = threadIdx.x;           // 0..127
  const int c0 = hg * 1024 + tid * 8;
  const int s = row & (SEQ - 1);
  float4 w4[8];
  #pragma unroll
  for (int e = 0; e < 8; e++) w4[e] = *(const float4*)(conv_w + (size_t)(c0 + e) * 4);
  float acc[8] = {0.f,0.f,0.f,0.f,0.f,0.f,0.f,0.f};
  #pragma unroll
  for (int j = 0; j < 4; j++) {
    int sj = s - 3 + j;
    if (sj >= 0) {
      bf16x8 x = *(const bf16x8*)(g1out + (size_t)(row - 3 + j) * NPAD + c0);
      #pragma unroll
      for (int e = 0; e < 8; e++) {
        float wj = (j == 0) ? w4[e].x : (j == 1) ? w4[e].y : (j == 2) ? w4[e].z : w4[e].w;
        acc[e] += wj * b2f((unsigned short)x[e]);
      }
    }
  }
  float sv[8], ssq = 0.f;
  #pragma unroll
  for (int e = 0; e < 8; e++) {
    sv[e] = acc[e] / (1.f + __expf(-acc[e]));
    ssq += sv[e] * sv[e];
  }
  // l2 over 128-ch head group = 16 consecutive lanes (within one wave)
  ssq += __shfl_xor(ssq, 1, 64);
  ssq += __shfl_xor(ssq, 2, 64);
  ssq += __shfl_xor(ssq, 4, 64);
  ssq += __shfl_xor(ssq, 8, 64);
  float scale = 1.f;
  if (hg < 4) {
    scale = rsqrtf(ssq + 1e-6f);
    if (hg < 2) scale *= 0.08838834764831845f;  // q: 1/sqrt(128)
  }
  bf16x8 o;
  #pragma unroll
  for (int e = 0; e < 8; e++) o[e] = (short)f2b(sv[e] * scale);
  *(bf16x8*)(qkv_act + (size_t)row * CONV_INNER + c0) = o;
}

// ---------------- conv_state output ----------------
__global__ void convstate_kernel(const unsigned short* __restrict__ g1out, float* __restrict__ out1)
{
  int idx = blockIdx.x * blockDim.x + threadIdx.x;
  int b = idx >> 15, rem = idx & 32767;
  int c = rem >> 2, j = rem & 3;
  out1[idx] = b2f(g1out[(size_t)(b * SEQ + SEQ - 4 + j) * NPAD + c]);
}

// ================= PASS 1: chunk-local W,U (UT transform) =================
__global__ __launch_bounds__(256, 2) void chunk_prep(
    const unsigned short* __restrict__ qact,
    const float* __restrict__ g_arr, const float* __restrict__ beta_arr,
    unsigned short* __restrict__ W_all, unsigned short* __restrict__ U_all)
{
  __shared__ __align__(16) char smem[73472];
  short* sKn = (short*)smem;                  // 64 x stride152; Vt (128x72) aliases
  short* sVt = (short*)smem;
  short* sKt = (short*)(smem + 19456);        // 128 x 72
  float* sA  = (float*)(smem + 37888);        // 64 x 68 fp32; Tb aliases
  short* sTb = (short*)(smem + 37888);        // 64 x 72 bf16
  float* sT  = (float*)(smem + 55296);        // 64 x 68 fp32
  float* sl  = (float*)(smem + 72704);
  float* sel = (float*)(smem + 72960);
  float* sbb = (float*)(smem + 73216);

  const int tid = threadIdx.x, lane = tid & 63, wid = tid >> 6;
  const int lane16 = lane & 15, quad = lane >> 4;
  const int cid = blockIdx.x;
  const int ch = cid & 31, h = (cid >> 5) & 31, b = cid >> 10;
  const int qh = h >> 1;
  const int row0 = b * SEQ + ch * 64;

  float gv = g_arr[(size_t)(row0 + lane) * 32 + h];
  float bb = beta_arr[(size_t)(row0 + lane) * 32 + h];
  float l = gv;
  #pragma unroll
  for (int off = 1; off < 64; off <<= 1) {
    float p = __shfl_up(l, off, 64);
    if (lane >= off) l += p;
  }
  float el = expf(l);
  if (wid == 0) { sl[lane] = l; sel[lane] = el; sbb[lane] = bb; }

  {
    int j = tid >> 2, kc = (tid & 3) * 32;
    const unsigned short* src = qact + (size_t)(row0 + j) * CONV_INNER + 2048 + qh * 128 + kc;
    #pragma unroll
    for (int u = 0; u < 4; u++) {
      bf16x8 r = *(const bf16x8*)(src + u * 8);
      *(bf16x8*)&sKn[j * 152 + kc + u * 8] = r;
    }
  }
  {
    const unsigned short* src = qact + (size_t)(row0 + lane) * CONV_INNER + 2048 + qh * 128 + wid * 32;
    float cj = bb * el;
    #pragma unroll
    for (int u = 0; u < 4; u++) {
      bf16x8 r = *(const bf16x8*)(src + u * 8);
      #pragma unroll
      for (int e = 0; e < 8; e++)
        sKt[(wid * 32 + u * 8 + e) * 72 + lane] = (short)f2b(b2f((unsigned short)r[e]) * cj);
    }
  }
  __syncthreads();

  {
    f32x4 accA[4];
    #pragma unroll
    for (int t = 0; t < 4; t++) accA[t] = f32x4{0.f, 0.f, 0.f, 0.f};
    #pragma unroll
    for (int ks = 0; ks < 4; ks++) {
      bf16x8 a = *(const bf16x8*)&sKn[(wid * 16 + lane16) * 152 + ks * 32 + quad * 8];
      #pragma unroll
      for (int jt = 0; jt < 4; jt++) {
        bf16x8 bfr = *(const bf16x8*)&sKn[(jt * 16 + lane16) * 152 + ks * 32 + quad * 8];
        accA[jt] = __builtin_amdgcn_mfma_f32_16x16x32_bf16(a, bfr, accA[jt], 0, 0, 0);
      }
    }
    #pragma unroll
    for (int jt = 0; jt < 4; jt++) {
      int j = jt * 16 + lane16;
      float lj = sl[j];
      #pragma unroll
      for (int r = 0; r < 4; r++) {
        int i = wid * 16 + quad * 4 + r;
        float v = (j < i) ? sbb[i] * expf(sl[i] - lj) * accA[jt][r] : 0.f;
        sA[i * 68 + j] = v;
      }
    }
  }
  __syncthreads();

  {
    const unsigned short* src = qact + (size_t)(row0 + lane) * CONV_INNER + 4096 + h * 128 + wid * 32;
    #pragma unroll
    for (int u = 0; u < 4; u++) {
      bf16x8 r = *(const bf16x8*)(src + u * 8);
      #pragma unroll
      for (int e = 0; e < 8; e++)
        sVt[(wid * 32 + u * 8 + e) * 72 + lane] = (short)f2b(b2f((unsigned short)r[e]) * bb);
    }
  }
  __syncthreads();

  if (wid == 0 && lane < 32) {
    int c = lane;
    float treg[32];
    treg[0] = (c == 0) ? 1.f : 0.f;
    #pragma unroll
    for (int i = 1; i < 32; i++) {
      float s = 0.f;
      #pragma unroll
      for (int j = 0; j < i; j++) s += sA[i * 68 + j] * treg[j];
      treg[i] = ((i == c) ? 1.f : 0.f) - s;
    }
    #pragma unroll
    for (int i = 0; i < 32; i++) sT[i * 68 + c] = treg[i];
  } else if (wid == 1 && lane < 32) {
    int c = lane;
    float treg[32];
    treg[0] = (c == 0) ? 1.f : 0.f;
    #pragma unroll
    for (int i = 1; i < 32; i++) {
      float s = 0.f;
      #pragma unroll
      for (int j = 0; j < i; j++) s += sA[(32 + i) * 68 + 32 + j] * treg[j];
      treg[i] = ((i == c) ? 1.f : 0.f) - s;
    }
    #pragma unroll
    for (int i = 0; i < 32; i++) sT[(32 + i) * 68 + 32 + c] = treg[i];
  } else if (wid == 2) {
    for (int e = lane; e < 1024; e += 64) sT[(e >> 5) * 68 + 32 + (e & 31)] = 0.f;
  }
  __syncthreads();

  {
    int i = tid & 31, c0 = (tid >> 5) * 4;
    float x[4] = {0.f, 0.f, 0.f, 0.f};
    #pragma unroll
    for (int j = 0; j < 32; j++) {
      float a = sA[(32 + i) * 68 + j];
      #pragma unroll
      for (int cc = 0; cc < 4; cc++) x[cc] += a * sT[j * 68 + c0 + cc];
    }
    #pragma unroll
    for (int cc = 0; cc < 4; cc++) sA[i * 68 + c0 + cc] = x[cc];
  }
  __syncthreads();
  {
    int i = tid & 31, c0 = (tid >> 5) * 4;
    float x[4] = {0.f, 0.f, 0.f, 0.f};
    #pragma unroll
    for (int j = 0; j < 32; j++) {
      float t2 = sT[(32 + i) * 68 + 32 + j];
      #pragma unroll
      for (int cc = 0; cc < 4; cc++) x[cc] += t2 * sA[j * 68 + c0 + cc];
    }
    #pragma unroll
    for (int cc = 0; cc < 4; cc++) sT[(32 + i) * 68 + c0 + cc] = -x[cc];
  }
  __syncthreads();
  #pragma unroll
  for (int ii = 0; ii < 16; ii++) {
    int e = tid + 256 * ii;
    int r = e >> 6, cc = e & 63;
    sTb[r * 72 + cc] = (short)f2b(sT[r * 68 + cc]);
  }
  __syncthreads();

  {
    f32x4 accW[8], accU[8];
    #pragma unroll
    for (int nt = 0; nt < 8; nt++) { accW[nt] = f32x4{0.f,0.f,0.f,0.f}; accU[nt] = f32x4{0.f,0.f,0.f,0.f}; }
    bf16x8 ta[2];
    #pragma unroll
    for (int ks = 0; ks < 2; ks++)
      ta[ks] = *(const bf16x8*)&sTb[(wid * 16 + lane16) * 72 + ks * 32 + quad * 8];
    #pragma unroll
    for (int nt = 0; nt < 8; nt++) {
      #pragma unroll
      for (int ks = 0; ks < 2; ks++) {
        bf16x8 bk = *(const bf16x8*)&sKt[(nt * 16 + lane16) * 72 + ks * 32 + quad * 8];
        accW[nt] = __builtin_amdgcn_mfma_f32_16x16x32_bf16(ta[ks], bk, accW[nt], 0, 0, 0);
        bf16x8 bv = *(const bf16x8*)&sVt[(nt * 16 + lane16) * 72 + ks * 32 + quad * 8];
        accU[nt] = __builtin_amdgcn_mfma_f32_16x16x32_bf16(ta[ks], bv, accU[nt], 0, 0, 0);
      }
    }
    unsigned short* Wg = W_all + (size_t)cid * 8192;
    unsigned short* Ug = U_all + (size_t)cid * 8192;
    #pragma unroll
    for (int nt = 0; nt < 8; nt++)
      #pragma unroll
      for (int r = 0; r < 4; r++) {
        int i = wid * 16 + quad * 4 + r, k = nt * 16 + lane16;
        Wg[i * 128 + k] = f2b(accW[nt][r]);
        Ug[i * 128 + k] = f2b(accU[nt][r]);
      }
  }
}

// ================= PASS 2: sequential chunk scan with MFMA =================
__global__ __launch_bounds__(256, 1) void chunk_scan(
    const unsigned short* __restrict__ qact,
    unsigned short* __restrict__ g1out,
    const float* __restrict__ g_arr,
    const float* __restrict__ norm_w,
    const unsigned short* __restrict__ W_all, const unsigned short* __restrict__ U_all,
    float* __restrict__ state_out)
{
  __shared__ __align__(16) char smem[142336];
  short* sS  = (short*)smem;                  // 128 x 136
  short* sQ  = (short*)(smem + 34816);        // 64 x 136
  short* sKn = (short*)(smem + 52224);        // 64 x 136; sM aliases
  short* sM  = (short*)(smem + 52224);
  short* sW  = (short*)(smem + 69632);        // 64 x 136
  short* sDt = (short*)(smem + 87040);        // 128 x 72
  short* sK2 = (short*)(smem + 105472);       // 128 x 72
  short* sZ  = (short*)(smem + 123904);       // 64 x 136
  float* sl  = (float*)(smem + 141312);
  float* sel = (float*)(smem + 141568);
  float* snw = (float*)(smem + 141824);

  const int tid = threadIdx.x, lane = tid & 63, wid = tid >> 6;
  const int lane16 = lane & 15, quad = lane >> 4;
  const int bh = blockIdx.x;
  const int h = bh & 31, b = bh >> 5, qh = h >> 1;

  for (int e = tid; e < 8704; e += 256) ((unsigned int*)sS)[e] = 0u;
  if (tid < 128) snw[tid] = norm_w[tid];
  float Sreg[2][8][4];
  #pragma unroll
  for (int vt2 = 0; vt2 < 2; vt2++)
    #pragma unroll
    for (int kt = 0; kt < 8; kt++)
      #pragma unroll
      for (int r = 0; r < 4; r++) Sreg[vt2][kt][r] = 0.f;

  for (int ch = 0; ch < 32; ch++) {
    const int cid = (bh << 5) + ch;
    const int row0 = b * SEQ + ch * 64;

    float gv = g_arr[(size_t)(row0 + lane) * 32 + h];
    float l = gv;
    #pragma unroll
    for (int off = 1; off < 64; off <<= 1) {
      float p = __shfl_up(l, off, 64);
      if (lane >= off) l += p;
    }
    float lC = __shfl(l, 63, 64);
    float elC = expf(lC);
    if (wid == 0) { sl[lane] = l; sel[lane] = expf(l); }

    {
      int j4 = tid >> 2, kc = (tid & 3) * 32;
      const unsigned short* sq = qact + (size_t)(row0 + j4) * CONV_INNER + qh * 128 + kc;
      const unsigned short* sk = sq + 2048;
      const unsigned short* sw = W_all + (size_t)cid * 8192 + j4 * 128 + kc;
      const unsigned short* sz = g1out + (size_t)(row0 + j4) * NPAD + 8192 + h * 128 + kc;
      #pragma unroll
      for (int u = 0; u < 4; u++) *(bf16x8*)&sQ[j4 * 136 + kc + u * 8] = *(const bf16x8*)(sq + u * 8);
      #pragma unroll
      for (int u = 0; u < 4; u++) *(bf16x8*)&sKn[j4 * 136 + kc + u * 8] = *(const bf16x8*)(sk + u * 8);
      #pragma unroll
      for (int u = 0; u < 4; u++) {
        bf16x8 rw = *(const bf16x8*)(sw + u * 8);
        #pragma unroll
        for (int e = 0; e < 8; e++) rw[e] = (short)(rw[e] ^ (short)0x8000);
        *(bf16x8*)&sW[j4 * 136 + kc + u * 8] = rw;
      }
      #pragma unroll
      for (int u = 0; u < 4; u++) *(bf16x8*)&sZ[j4 * 136 + kc + u * 8] = *(const bf16x8*)(sz + u * 8);
    }
    {
      const unsigned short* src = qact + (size_t)(row0 + lane) * CONV_INNER + 2048 + qh * 128 + wid * 32;
      float s2 = expf(lC - l);
      #pragma unroll
      for (int u = 0; u < 4; u++) {
        bf16x8 r = *(const bf16x8*)(src + u * 8);
        #pragma unroll
        for (int e = 0; e < 8; e++)
          sK2[(wid * 32 + u * 8 + e) * 72 + lane] = (short)f2b(b2f((unsigned short)r[e]) * s2);
      }
    }
    float uv[8][4];
    {
      const unsigned short* Ug = U_all + (size_t)cid * 8192;
      #pragma unroll
      for (int nt = 0; nt < 8; nt++)
        #pragma unroll
        for (int r = 0; r < 4; r++)
          uv[nt][r] = b2f(Ug[(wid * 16 + quad * 4 + r) * 128 + nt * 16 + lane16]);
    }
    __syncthreads();   // B1

    {
      f32x4 aD[8];
      #pragma unroll
      for (int nt = 0; nt < 8; nt++) aD[nt] = f32x4{0.f,0.f,0.f,0.f};
      #pragma unroll
      for (int ks = 0; ks < 4; ks++) {
        bf16x8 a = *(const bf16x8*)&sW[(wid * 16 + lane16) * 136 + ks * 32 + quad * 8];
        #pragma unroll
        for (int nt = 0; nt < 8; nt++) {
          bf16x8 bfr = *(const bf16x8*)&sS[(nt * 16 + lane16) * 136 + ks * 32 + quad * 8];
          aD[nt] = __builtin_amdgcn_mfma_f32_16x16x32_bf16(a, bfr, aD[nt], 0, 0, 0);
        }
      }
      #pragma unroll
      for (int nt = 0; nt < 8; nt++)
        #pragma unroll
        for (int r = 0; r < 4; r++)
          sDt[(nt * 16 + lane16) * 72 + wid * 16 + quad * 4 + r] = (short)f2b(aD[nt][r] + uv[nt][r]);
    }

    f32x4 aM[4];
    #pragma unroll
    for (int jt = 0; jt < 4; jt++) aM[jt] = f32x4{0.f,0.f,0.f,0.f};
    #pragma unroll
    for (int ks = 0; ks < 4; ks++) {
      bf16x8 a = *(const bf16x8*)&sQ[(wid * 16 + lane16) * 136 + ks * 32 + quad * 8];
      #pragma unroll
      for (int jt = 0; jt < 4; jt++) {
        bf16x8 bfr = *(const bf16x8*)&sKn[(jt * 16 + lane16) * 136 + ks * 32 + quad * 8];
        aM[jt] = __builtin_amdgcn_mfma_f32_16x16x32_bf16(a, bfr, aM[jt], 0, 0, 0);
      }
    }
    __syncthreads();   // B2

    #pragma unroll
    for (int jt = 0; jt < 4; jt++) {
      int j = jt * 16 + lane16;
      float lj = sl[j];
      #pragma unroll
      for (int r = 0; r < 4; r++) {
        int i = wid * 16 + quad * 4 + r;
        float m = (j <= i) ? expf(sl[i] - lj) * aM[jt][r] : 0.f;
        sM[i * 72 + j] = (short)f2b(m);
      }
    }
    f32x4 aO[8];
    #pragma unroll
    for (int nt = 0; nt < 8; nt++) aO[nt] = f32x4{0.f,0.f,0.f,0.f};
    #pragma unroll
    for (int ks = 0; ks < 4; ks++) {
      bf16x8 a = *(const bf16x8*)&sQ[(wid * 16 + lane16) * 136 + ks * 32 + quad * 8];
      #pragma unroll
      for (int nt = 0; nt < 8; nt++) {
        bf16x8 bfr = *(const bf16x8*)&sS[(nt * 16 + lane16) * 136 + ks * 32 + quad * 8];
        aO[nt] = __builtin_amdgcn_mfma_f32_16x16x32_bf16(a, bfr, aO[nt], 0, 0, 0);
      }
    }
    #pragma unroll
    for (int r = 0; r < 4; r++) {
      float eli = sel[wid * 16 + quad * 4 + r];
      #pragma unroll
      for (int nt = 0; nt < 8; nt++) aO[nt][r] *= eli;
    }
    __syncthreads();   // B3

    #pragma unroll
    for (int ks = 0; ks < 2; ks++) {
      bf16x8 a = *(const bf16x8*)&sM[(wid * 16 + lane16) * 72 + ks * 32 + quad * 8];
      #pragma unroll
      for (int nt = 0; nt < 8; nt++) {
        bf16x8 bfr = *(const bf16x8*)&sDt[(nt * 16 + lane16) * 72 + ks * 32 + quad * 8];
        aO[nt] = __builtin_amdgcn_mfma_f32_16x16x32_bf16(a, bfr, aO[nt], 0, 0, 0);
      }
    }
    #pragma unroll
    for (int r = 0; r < 4; r++) {
      float ss = 0.f;
      #pragma unroll
      for (int nt = 0; nt < 8; nt++) ss += aO[nt][r] * aO[nt][r];
      ss += __shfl_xor(ss, 1, 64);
      ss += __shfl_xor(ss, 2, 64);
      ss += __shfl_xor(ss, 4, 64);
      ss += __shfl_xor(ss, 8, 64);
      float rinv = rsqrtf(ss * (1.f / 128.f) + 1e-6f);
      int i = wid * 16 + quad * 4 + r;
      size_t grow = (size_t)(row0 + i) * NPAD + h * 128;
      #pragma unroll
      for (int nt = 0; nt < 8; nt++) {
        int v = nt * 16 + lane16;
        float zv = b2f((unsigned short)sZ[i * 136 + v]);
        float zg = zv / (1.f + __expf(-zv));
        float y = snw[v] * (aO[nt][r] * rinv) * zg;
        g1out[grow + v] = f2b(y);
      }
    }
    #pragma unroll
    for (int vt2 = 0; vt2 < 2; vt2++) {
      f32x4 aS[8];
      #pragma unroll
      for (int kt = 0; kt < 8; kt++) aS[kt] = f32x4{0.f,0.f,0.f,0.f};
      #pragma unroll
      for (int ks = 0; ks < 2; ks++) {
        bf16x8 a = *(const bf16x8*)&sDt[((wid * 2 + vt2) * 16 + lane16) * 72 + ks * 32 + quad * 8];
        #pragma unroll
        for (int kt = 0; kt < 8; kt++) {
          bf16x8 bfr = *(const bf16x8*)&sK2[(kt * 16 + lane16) * 72 + ks * 32 + quad * 8];
          aS[kt] = __builtin_amdgcn_mfma_f32_16x16x32_bf16(a, bfr, aS[kt], 0, 0, 0);
        }
      }
      #pragma unroll
      for (int kt = 0; kt < 8; kt++)
        #pragma unroll
        for (int r = 0; r < 4; r++)
          Sreg[vt2][kt][r] = elC * Sreg[vt2][kt][r] + aS[kt][r];
    }
    __syncthreads();   // B4
    #pragma unroll
    for (int vt2 = 0; vt2 < 2; vt2++)
      #pragma unroll
      for (int kt = 0; kt < 8; kt++)
        #pragma unroll
        for (int r = 0; r < 4; r++)
          sS[((wid * 2 + vt2) * 16 + quad * 4 + r) * 136 + kt * 16 + lane16] = (short)f2b(Sreg[vt2][kt][r]);
    __syncthreads();   // B5
  }

  float* so = state_out + (size_t)bh * 16384;
  #pragma unroll
  for (int vt2 = 0; vt2 < 2; vt2++)
    #pragma unroll
    for (int kt = 0; kt < 8; kt++)
      #pragma unroll
      for (int r = 0; r < 4; r++)
        so[((wid * 2 + vt2) * 16 + quad * 4 + r) * 128 + kt * 16 + lane16] = Sreg[vt2][kt][r];
}

extern "C" void kernel_launch(void* const* d_in, const int* in_sizes, int n_in,
                              void* d_out, int out_size, void* d_ws, size_t ws_size,
                              hipStream_t stream)
{
  const float* hidden  = (const float*)d_in[0];
  const float* W_qkv   = (const float*)d_in[1];
  const float* W_z     = (const float*)d_in[2];
  const float* W_a     = (const float*)d_in[3];
  const float* W_b     = (const float*)d_in[4];
  const float* conv_w  = (const float*)d_in[5];
  const float* A_log   = (const float*)d_in[6];
  const float* dt_bias = (const float*)d_in[7];
  const float* norm_w  = (const float*)d_in[8];
  const float* W_out   = (const float*)d_in[9];

  char* ws = (char*)d_ws;
  unsigned short* hbf   = (unsigned short*)(ws);                 // [4096][2048] bf16
  unsigned short* Wcat  = (unsigned short*)(ws + 16777216ull);   // [12416][2048] bf16
  unsigned short* Woutb = (unsigned short*)(ws + 67633152ull);   // [2048][4096] bf16
  unsigned short* g1out = (unsigned short*)(ws + 84410368ull);   // [4096][12416] bf16
  unsigned short* qact  = (unsigned short*)(ws + 186122240ull);  // [4096][8192] bf16
  float* g_arr          = (float*)(ws + 253231104ull);           // [4096][32]
  float* beta           = (float*)(ws + 253755392ull);           // [4096][32]
  unsigned short* W_all = (unsigned short*)(ws);                 // aliases hbf (dead after GEMM1)
  unsigned short* U_all = (unsigned short*)(ws + 33554432ull);   // aliases Wcat tail

  float* out0 = (float*)d_out;          // (2,2048,2048) fp32
  float* out1 = out0 + 8388608;         // conv_state (2,8192,4)
  float* out2 = out0 + 8454144;         // state (2,32,128,128)

  cast_kernel<<<8192,  256, 0, stream>>>(hidden, hbf, 2097152);
  cast_kernel<<<16384, 256, 0, stream>>>(W_qkv, Wcat, 4194304);
  cast_kernel<<<8192,  256, 0, stream>>>(W_z,   Wcat + 8192ull  * 2048, 2097152);
  cast_kernel<<<64,    256, 0, stream>>>(W_a,   Wcat + 12288ull * 2048, 16384);
  cast_kernel<<<64,    256, 0, stream>>>(W_b,   Wcat + 12320ull * 2048, 16384);
  cast_kernel<<<8192,  256, 0, stream>>>(W_out, Woutb, 2097152);

  gemm_bt<true><<<dim3(97, 32), 256, 0, stream>>>(hbf, Wcat, g1out, 2048, 2048, 2048, NPAD, NTOT);
  gebeta_kernel<<<512, 256, 0, stream>>>(g1out, A_log, dt_bias, g_arr, beta);
  conv_kernel<<<dim3(4096, 8), 128, 0, stream>>>(g1out, conv_w, qact);
  convstate_kernel<<<256, 256, 0, stream>>>(g1out, out1);

  chunk_prep<<<2048, 256, 0, stream>>>(qact, g_arr, beta, W_all, U_all);
  chunk_scan<<<64, 256, 0, stream>>>(qact, g1out, g_arr, norm_w, W_all, U_all, out2);

  gemm_bt<false><<<dim3(16, 32), 256, 0, stream>>>(g1out, Woutb, out0, 4096, NPAD, 4096, 2048, 2048);
}

// Round 4
// 1059.835 us; speedup vs baseline: 3.5532x; 1.0557x over previous
//
#include <hip/hip_runtime.h>
#include <hip/hip_bf16.h>
#include <cstdint>

#define SEQ 2048
#define NPAD 12416      // 97*128, padded N for GEMM1
#define NTOT 12352      // qkv(8192) + z(4096) + a(32) + b(32)
#define CONV_INNER 8192

typedef __attribute__((ext_vector_type(8))) short bf16x8;
typedef __attribute__((ext_vector_type(4))) float f32x4;

__device__ __forceinline__ float b2f(unsigned short u) {
  union { unsigned int i; float f; } x; x.i = ((unsigned int)u) << 16; return x.f;
}
__device__ __forceinline__ unsigned short f2b(float f) {
  __hip_bfloat16 h = __float2bfloat16(f);
  return *reinterpret_cast<unsigned short*>(&h);
}
__device__ __forceinline__ void load_lds16(const short* g, short* l) {
  __builtin_amdgcn_global_load_lds(
      (__attribute__((address_space(1))) void*)(g),
      (__attribute__((address_space(3))) void*)(l), 16, 0, 0);
}

// ---------------- fp32 -> bf16 cast ----------------
__global__ void cast_kernel(const float* __restrict__ in, unsigned short* __restrict__ out, int n4) {
  int i = blockIdx.x * blockDim.x + threadIdx.x;
  if (i >= n4) return;
  float4 v = ((const float4*)in)[i];
  ushort4 o;
  o.x = f2b(v.x); o.y = f2b(v.y); o.z = f2b(v.z); o.w = f2b(v.w);
  ((ushort4*)out)[i] = o;
}

// ---------------- bf16 MFMA GEMM: C[m][n] = sum_k A[m][k]*B[n][k] ----------------
// m97 structure + XOR-swizzled LDS (conflict-free) + BK=64 double-stage.
// LDS slot (row r, chunk c) holds global chunk (c ^ ((r>>1)&3)) of row r.
template<bool OUT_BF16>
__global__ __launch_bounds__(256) void gemm_bt(
    const unsigned short* __restrict__ A,   // [M][lda] bf16
    const unsigned short* __restrict__ Bm,  // [Nrows][ldb] bf16
    void* __restrict__ Cout, int K, int lda, int ldb, int ldc, int nmax)
{
  __shared__ __align__(16) short lA[2][128 * 32];
  __shared__ __align__(16) short lB[2][128 * 32];
  const int tid = threadIdx.x;
  const int lane = tid & 63, wid = tid >> 6;
  const int lane16 = lane & 15, quad = lane >> 4;
  const int wm = (wid & 1) * 64, wn = (wid >> 1) * 64;
  const int m0 = blockIdx.y * 128, n0 = blockIdx.x * 128;
  const int srow = wid * 16 + (lane >> 2);                  // staged tile row
  const int scol = (((lane & 3) ^ ((lane >> 3) & 3))) * 8;  // swizzled source chunk
  const int rchunk = (quad ^ ((lane16 >> 1) & 3)) * 8;      // swizzled fragment chunk

  f32x4 acc[4][4];
  #pragma unroll
  for (int i = 0; i < 4; i++)
    #pragma unroll
    for (int j = 0; j < 4; j++)
      acc[i][j] = f32x4{0.f, 0.f, 0.f, 0.f};

  const short* As = (const short*)A;
  const short* Bs = (const short*)Bm;
  short* lA0s[2] = { &lA[0][(wid * 16) * 32], &lA[1][(wid * 16) * 32] };
  short* lA1s[2] = { &lA[0][(64 + wid * 16) * 32], &lA[1][(64 + wid * 16) * 32] };
  short* lB0s[2] = { &lB[0][(wid * 16) * 32], &lB[1][(wid * 16) * 32] };
  short* lB1s[2] = { &lB[0][(64 + wid * 16) * 32], &lB[1][(64 + wid * 16) * 32] };
  const short* ga0 = As + (size_t)(m0 + srow) * lda + scol;
  const short* ga1 = As + (size_t)(m0 + 64 + srow) * lda + scol;
  const short* gb0 = Bs + (size_t)(n0 + srow) * ldb + scol;
  const short* gb1 = Bs + (size_t)(n0 + 64 + srow) * ldb + scol;

  for (int kb = 0; kb < K; kb += 64) {
    #pragma unroll
    for (int st = 0; st < 2; st++) {
      int ko = kb + st * 32;
      load_lds16(ga0 + ko, lA0s[st]);
      load_lds16(ga1 + ko, lA1s[st]);
      load_lds16(gb0 + ko, lB0s[st]);
      load_lds16(gb1 + ko, lB1s[st]);
    }
    __syncthreads();   // drains vmcnt -> both stages complete
    #pragma unroll
    for (int st = 0; st < 2; st++) {
      bf16x8 af[4], bfr[4];
      #pragma unroll
      for (int t = 0; t < 4; t++) af[t]  = *(const bf16x8*)&lA[st][(wm + t * 16 + lane16) * 32 + rchunk];
      #pragma unroll
      for (int t = 0; t < 4; t++) bfr[t] = *(const bf16x8*)&lB[st][(wn + t * 16 + lane16) * 32 + rchunk];
      #pragma unroll
      for (int i = 0; i < 4; i++)
        #pragma unroll
        for (int j = 0; j < 4; j++)
          acc[i][j] = __builtin_amdgcn_mfma_f32_16x16x32_bf16(af[i], bfr[j], acc[i][j], 0, 0, 0);
    }
    __syncthreads();   // all reads done before next overwrite
  }

  #pragma unroll
  for (int i = 0; i < 4; i++) {
    #pragma unroll
    for (int j = 0; j < 4; j++) {
      int n = n0 + wn + j * 16 + lane16;
      if (n >= nmax) continue;
      #pragma unroll
      for (int r = 0; r < 4; r++) {
        int m = m0 + wm + i * 16 + quad * 4 + r;
        float v = acc[i][j][r];
        if (OUT_BF16) ((unsigned short*)Cout)[(size_t)m * ldc + n] = f2b(v);
        else          ((float*)Cout)[(size_t)m * ldc + n] = v;
      }
    }
  }
}

// ---------------- gates: g (log decay) and beta ----------------
__global__ void gebeta_kernel(const unsigned short* __restrict__ g1out,
                              const float* __restrict__ A_log, const float* __restrict__ dt_bias,
                              float* __restrict__ g_out, float* __restrict__ beta)
{
  int idx = blockIdx.x * blockDim.x + threadIdx.x;  // 131072 = 4096*32
  int r = idx >> 5, n = idx & 31;
  float a = b2f(g1out[(size_t)r * NPAD + 12288 + n]) + dt_bias[n];
  float sp = (a > 20.f) ? a : log1pf(expf(a));
  g_out[idx] = -expf(A_log[n]) * sp;
  float bv = b2f(g1out[(size_t)r * NPAD + 12320 + n]);
  beta[idx] = 1.f / (1.f + expf(-bv));
}

// ---------------- conv(4) + silu + l2norm(q,k), 8 ch/thread ----------------
__global__ __launch_bounds__(128) void conv_kernel(
    const unsigned short* __restrict__ g1out, const float* __restrict__ conv_w,
    unsigned short* __restrict__ qkv_act)
{
  const int row = blockIdx.x;            // b*SEQ + s
  const int hg  = blockIdx.y;            // 0..7 (1024 channels each)
  const int tid = threadIdx.x;           // 0..127
  const int c0 = hg * 1024 + tid * 8;
  const int s = row & (SEQ - 1);
  float4 w4[8];
  #pragma unroll
  for (int e = 0; e < 8; e++) w4[e] = *(const float4*)(conv_w + (size_t)(c0 + e) * 4);
  float acc[8] = {0.f,0.f,0.f,0.f,0.f,0.f,0.f,0.f};
  #pragma unroll
  for (int j = 0; j < 4; j++) {
    int sj = s - 3 + j;
    if (sj >= 0) {
      bf16x8 x = *(const bf16x8*)(g1out + (size_t)(row - 3 + j) * NPAD + c0);
      #pragma unroll
      for (int e = 0; e < 8; e++) {
        float wj = (j == 0) ? w4[e].x : (j == 1) ? w4[e].y : (j == 2) ? w4[e].z : w4[e].w;
        acc[e] += wj * b2f((unsigned short)x[e]);
      }
    }
  }
  float sv[8], ssq = 0.f;
  #pragma unroll
  for (int e = 0; e < 8; e++) {
    sv[e] = acc[e] / (1.f + __expf(-acc[e]));
    ssq += sv[e] * sv[e];
  }
  ssq += __shfl_xor(ssq, 1, 64);
  ssq += __shfl_xor(ssq, 2, 64);
  ssq += __shfl_xor(ssq, 4, 64);
  ssq += __shfl_xor(ssq, 8, 64);
  float scale = 1.f;
  if (hg < 4) {
    scale = rsqrtf(ssq + 1e-6f);
    if (hg < 2) scale *= 0.08838834764831845f;  // q: 1/sqrt(128)
  }
  bf16x8 o;
  #pragma unroll
  for (int e = 0; e < 8; e++) o[e] = (short)f2b(sv[e] * scale);
  *(bf16x8*)(qkv_act + (size_t)row * CONV_INNER + c0) = o;
}

// ---------------- conv_state output ----------------
__global__ void convstate_kernel(const unsigned short* __restrict__ g1out, float* __restrict__ out1)
{
  int idx = blockIdx.x * blockDim.x + threadIdx.x;
  int b = idx >> 15, rem = idx & 32767;
  int c = rem >> 2, j = rem & 3;
  out1[idx] = b2f(g1out[(size_t)(b * SEQ + SEQ - 4 + j) * NPAD + c]);
}

// ================= PASS 1: chunk-local W,U (UT transform) =================
__global__ __launch_bounds__(256, 2) void chunk_prep(
    const unsigned short* __restrict__ qact,
    const float* __restrict__ g_arr, const float* __restrict__ beta_arr,
    unsigned short* __restrict__ W_all, unsigned short* __restrict__ U_all)
{
  __shared__ __align__(16) char smem[73472];
  short* sKn = (short*)smem;                  // 64 x stride152; Vt (128x72) aliases
  short* sVt = (short*)smem;
  short* sKt = (short*)(smem + 19456);        // 128 x 72
  float* sA  = (float*)(smem + 37888);        // 64 x 68 fp32; Tb aliases
  short* sTb = (short*)(smem + 37888);        // 64 x 72 bf16
  float* sT  = (float*)(smem + 55296);        // 64 x 68 fp32
  float* sl  = (float*)(smem + 72704);
  float* sel = (float*)(smem + 72960);
  float* sbb = (float*)(smem + 73216);

  const int tid = threadIdx.x, lane = tid & 63, wid = tid >> 6;
  const int lane16 = lane & 15, quad = lane >> 4;
  const int cid = blockIdx.x;
  const int ch = cid & 31, h = (cid >> 5) & 31, b = cid >> 10;
  const int qh = h >> 1;
  const int row0 = b * SEQ + ch * 64;

  float gv = g_arr[(size_t)(row0 + lane) * 32 + h];
  float bb = beta_arr[(size_t)(row0 + lane) * 32 + h];
  float l = gv;
  #pragma unroll
  for (int off = 1; off < 64; off <<= 1) {
    float p = __shfl_up(l, off, 64);
    if (lane >= off) l += p;
  }
  float el = expf(l);
  if (wid == 0) { sl[lane] = l; sel[lane] = el; sbb[lane] = bb; }

  {
    int j = tid >> 2, kc = (tid & 3) * 32;
    const unsigned short* src = qact + (size_t)(row0 + j) * CONV_INNER + 2048 + qh * 128 + kc;
    #pragma unroll
    for (int u = 0; u < 4; u++) {
      bf16x8 r = *(const bf16x8*)(src + u * 8);
      *(bf16x8*)&sKn[j * 152 + kc + u * 8] = r;
    }
  }
  {
    const unsigned short* src = qact + (size_t)(row0 + lane) * CONV_INNER + 2048 + qh * 128 + wid * 32;
    float cj = bb * el;
    #pragma unroll
    for (int u = 0; u < 4; u++) {
      bf16x8 r = *(const bf16x8*)(src + u * 8);
      #pragma unroll
      for (int e = 0; e < 8; e++)
        sKt[(wid * 32 + u * 8 + e) * 72 + lane] = (short)f2b(b2f((unsigned short)r[e]) * cj);
    }
  }
  __syncthreads();

  {
    f32x4 accA[4];
    #pragma unroll
    for (int t = 0; t < 4; t++) accA[t] = f32x4{0.f, 0.f, 0.f, 0.f};
    #pragma unroll
    for (int ks = 0; ks < 4; ks++) {
      bf16x8 a = *(const bf16x8*)&sKn[(wid * 16 + lane16) * 152 + ks * 32 + quad * 8];
      #pragma unroll
      for (int jt = 0; jt < 4; jt++) {
        bf16x8 bfr = *(const bf16x8*)&sKn[(jt * 16 + lane16) * 152 + ks * 32 + quad * 8];
        accA[jt] = __builtin_amdgcn_mfma_f32_16x16x32_bf16(a, bfr, accA[jt], 0, 0, 0);
      }
    }
    #pragma unroll
    for (int jt = 0; jt < 4; jt++) {
      int j = jt * 16 + lane16;
      float lj = sl[j];
      #pragma unroll
      for (int r = 0; r < 4; r++) {
        int i = wid * 16 + quad * 4 + r;
        float v = (j < i) ? sbb[i] * expf(sl[i] - lj) * accA[jt][r] : 0.f;
        sA[i * 68 + j] = v;
      }
    }
  }
  __syncthreads();

  {
    const unsigned short* src = qact + (size_t)(row0 + lane) * CONV_INNER + 4096 + h * 128 + wid * 32;
    #pragma unroll
    for (int u = 0; u < 4; u++) {
      bf16x8 r = *(const bf16x8*)(src + u * 8);
      #pragma unroll
      for (int e = 0; e < 8; e++)
        sVt[(wid * 32 + u * 8 + e) * 72 + lane] = (short)f2b(b2f((unsigned short)r[e]) * bb);
    }
  }
  __syncthreads();

  if (wid == 0 && lane < 32) {
    int c = lane;
    float treg[32];
    treg[0] = (c == 0) ? 1.f : 0.f;
    #pragma unroll
    for (int i = 1; i < 32; i++) {
      float s = 0.f;
      #pragma unroll
      for (int j = 0; j < i; j++) s += sA[i * 68 + j] * treg[j];
      treg[i] = ((i == c) ? 1.f : 0.f) - s;
    }
    #pragma unroll
    for (int i = 0; i < 32; i++) sT[i * 68 + c] = treg[i];
  } else if (wid == 1 && lane < 32) {
    int c = lane;
    float treg[32];
    treg[0] = (c == 0) ? 1.f : 0.f;
    #pragma unroll
    for (int i = 1; i < 32; i++) {
      float s = 0.f;
      #pragma unroll
      for (int j = 0; j < i; j++) s += sA[(32 + i) * 68 + 32 + j] * treg[j];
      treg[i] = ((i == c) ? 1.f : 0.f) - s;
    }
    #pragma unroll
    for (int i = 0; i < 32; i++) sT[(32 + i) * 68 + 32 + c] = treg[i];
  } else if (wid == 2) {
    for (int e = lane; e < 1024; e += 64) sT[(e >> 5) * 68 + 32 + (e & 31)] = 0.f;
  }
  __syncthreads();

  {
    int i = tid & 31, c0 = (tid >> 5) * 4;
    float x[4] = {0.f, 0.f, 0.f, 0.f};
    #pragma unroll
    for (int j = 0; j < 32; j++) {
      float a = sA[(32 + i) * 68 + j];
      #pragma unroll
      for (int cc = 0; cc < 4; cc++) x[cc] += a * sT[j * 68 + c0 + cc];
    }
    #pragma unroll
    for (int cc = 0; cc < 4; cc++) sA[i * 68 + c0 + cc] = x[cc];
  }
  __syncthreads();
  {
    int i = tid & 31, c0 = (tid >> 5) * 4;
    float x[4] = {0.f, 0.f, 0.f, 0.f};
    #pragma unroll
    for (int j = 0; j < 32; j++) {
      float t2 = sT[(32 + i) * 68 + 32 + j];
      #pragma unroll
      for (int cc = 0; cc < 4; cc++) x[cc] += t2 * sA[j * 68 + c0 + cc];
    }
    #pragma unroll
    for (int cc = 0; cc < 4; cc++) sT[(32 + i) * 68 + c0 + cc] = -x[cc];
  }
  __syncthreads();
  #pragma unroll
  for (int ii = 0; ii < 16; ii++) {
    int e = tid + 256 * ii;
    int r = e >> 6, cc = e & 63;
    sTb[r * 72 + cc] = (short)f2b(sT[r * 68 + cc]);
  }
  __syncthreads();

  {
    f32x4 accW[8], accU[8];
    #pragma unroll
    for (int nt = 0; nt < 8; nt++) { accW[nt] = f32x4{0.f,0.f,0.f,0.f}; accU[nt] = f32x4{0.f,0.f,0.f,0.f}; }
    bf16x8 ta[2];
    #pragma unroll
    for (int ks = 0; ks < 2; ks++)
      ta[ks] = *(const bf16x8*)&sTb[(wid * 16 + lane16) * 72 + ks * 32 + quad * 8];
    #pragma unroll
    for (int nt = 0; nt < 8; nt++) {
      #pragma unroll
      for (int ks = 0; ks < 2; ks++) {
        bf16x8 bk = *(const bf16x8*)&sKt[(nt * 16 + lane16) * 72 + ks * 32 + quad * 8];
        accW[nt] = __builtin_amdgcn_mfma_f32_16x16x32_bf16(ta[ks], bk, accW[nt], 0, 0, 0);
        bf16x8 bv = *(const bf16x8*)&sVt[(nt * 16 + lane16) * 72 + ks * 32 + quad * 8];
        accU[nt] = __builtin_amdgcn_mfma_f32_16x16x32_bf16(ta[ks], bv, accU[nt], 0, 0, 0);
      }
    }
    unsigned short* Wg = W_all + (size_t)cid * 8192;
    unsigned short* Ug = U_all + (size_t)cid * 8192;
    #pragma unroll
    for (int nt = 0; nt < 8; nt++)
      #pragma unroll
      for (int r = 0; r < 4; r++) {
        int i = wid * 16 + quad * 4 + r, k = nt * 16 + lane16;
        Wg[i * 128 + k] = f2b(accW[nt][r]);
        Ug[i * 128 + k] = f2b(accU[nt][r]);
      }
  }
}

// ================= PASS 2: sequential chunk scan with MFMA =================
__global__ __launch_bounds__(256, 1) void chunk_scan(
    const unsigned short* __restrict__ qact,
    unsigned short* __restrict__ g1out,
    const float* __restrict__ g_arr,
    const float* __restrict__ norm_w,
    const unsigned short* __restrict__ W_all, const unsigned short* __restrict__ U_all,
    float* __restrict__ state_out)
{
  __shared__ __align__(16) char smem[142336];
  short* sS  = (short*)smem;                  // 128 x 136
  short* sQ  = (short*)(smem + 34816);        // 64 x 136
  short* sKn = (short*)(smem + 52224);        // 64 x 136; sM aliases
  short* sM  = (short*)(smem + 52224);
  short* sW  = (short*)(smem + 69632);        // 64 x 136
  short* sDt = (short*)(smem + 87040);        // 128 x 72
  short* sK2 = (short*)(smem + 105472);       // 128 x 72
  short* sZ  = (short*)(smem + 123904);       // 64 x 136
  float* sl  = (float*)(smem + 141312);
  float* sel = (float*)(smem + 141568);
  float* snw = (float*)(smem + 141824);

  const int tid = threadIdx.x, lane = tid & 63, wid = tid >> 6;
  const int lane16 = lane & 15, quad = lane >> 4;
  const int bh = blockIdx.x;
  const int h = bh & 31, b = bh >> 5, qh = h >> 1;

  for (int e = tid; e < 8704; e += 256) ((unsigned int*)sS)[e] = 0u;
  if (tid < 128) snw[tid] = norm_w[tid];
  float Sreg[2][8][4];
  #pragma unroll
  for (int vt2 = 0; vt2 < 2; vt2++)
    #pragma unroll
    for (int kt = 0; kt < 8; kt++)
      #pragma unroll
      for (int r = 0; r < 4; r++) Sreg[vt2][kt][r] = 0.f;

  for (int ch = 0; ch < 32; ch++) {
    const int cid = (bh << 5) + ch;
    const int row0 = b * SEQ + ch * 64;

    float gv = g_arr[(size_t)(row0 + lane) * 32 + h];
    float l = gv;
    #pragma unroll
    for (int off = 1; off < 64; off <<= 1) {
      float p = __shfl_up(l, off, 64);
      if (lane >= off) l += p;
    }
    float lC = __shfl(l, 63, 64);
    float elC = expf(lC);
    if (wid == 0) { sl[lane] = l; sel[lane] = expf(l); }

    {
      int j4 = tid >> 2, kc = (tid & 3) * 32;
      const unsigned short* sq = qact + (size_t)(row0 + j4) * CONV_INNER + qh * 128 + kc;
      const unsigned short* sk = sq + 2048;
      const unsigned short* sw = W_all + (size_t)cid * 8192 + j4 * 128 + kc;
      const unsigned short* sz = g1out + (size_t)(row0 + j4) * NPAD + 8192 + h * 128 + kc;
      #pragma unroll
      for (int u = 0; u < 4; u++) *(bf16x8*)&sQ[j4 * 136 + kc + u * 8] = *(const bf16x8*)(sq + u * 8);
      #pragma unroll
      for (int u = 0; u < 4; u++) *(bf16x8*)&sKn[j4 * 136 + kc + u * 8] = *(const bf16x8*)(sk + u * 8);
      #pragma unroll
      for (int u = 0; u < 4; u++) {
        bf16x8 rw = *(const bf16x8*)(sw + u * 8);
        #pragma unroll
        for (int e = 0; e < 8; e++) rw[e] = (short)(rw[e] ^ (short)0x8000);
        *(bf16x8*)&sW[j4 * 136 + kc + u * 8] = rw;
      }
      #pragma unroll
      for (int u = 0; u < 4; u++) *(bf16x8*)&sZ[j4 * 136 + kc + u * 8] = *(const bf16x8*)(sz + u * 8);
    }
    {
      const unsigned short* src = qact + (size_t)(row0 + lane) * CONV_INNER + 2048 + qh * 128 + wid * 32;
      float s2 = expf(lC - l);
      #pragma unroll
      for (int u = 0; u < 4; u++) {
        bf16x8 r = *(const bf16x8*)(src + u * 8);
        #pragma unroll
        for (int e = 0; e < 8; e++)
          sK2[(wid * 32 + u * 8 + e) * 72 + lane] = (short)f2b(b2f((unsigned short)r[e]) * s2);
      }
    }
    float uv[8][4];
    {
      const unsigned short* Ug = U_all + (size_t)cid * 8192;
      #pragma unroll
      for (int nt = 0; nt < 8; nt++)
        #pragma unroll
        for (int r = 0; r < 4; r++)
          uv[nt][r] = b2f(Ug[(wid * 16 + quad * 4 + r) * 128 + nt * 16 + lane16]);
    }
    __syncthreads();   // B1

    {
      f32x4 aD[8];
      #pragma unroll
      for (int nt = 0; nt < 8; nt++) aD[nt] = f32x4{0.f,0.f,0.f,0.f};
      #pragma unroll
      for (int ks = 0; ks < 4; ks++) {
        bf16x8 a = *(const bf16x8*)&sW[(wid * 16 + lane16) * 136 + ks * 32 + quad * 8];
        #pragma unroll
        for (int nt = 0; nt < 8; nt++) {
          bf16x8 bfr = *(const bf16x8*)&sS[(nt * 16 + lane16) * 136 + ks * 32 + quad * 8];
          aD[nt] = __builtin_amdgcn_mfma_f32_16x16x32_bf16(a, bfr, aD[nt], 0, 0, 0);
        }
      }
      #pragma unroll
      for (int nt = 0; nt < 8; nt++)
        #pragma unroll
        for (int r = 0; r < 4; r++)
          sDt[(nt * 16 + lane16) * 72 + wid * 16 + quad * 4 + r] = (short)f2b(aD[nt][r] + uv[nt][r]);
    }

    f32x4 aM[4];
    #pragma unroll
    for (int jt = 0; jt < 4; jt++) aM[jt] = f32x4{0.f,0.f,0.f,0.f};
    #pragma unroll
    for (int ks = 0; ks < 4; ks++) {
      bf16x8 a = *(const bf16x8*)&sQ[(wid * 16 + lane16) * 136 + ks * 32 + quad * 8];
      #pragma unroll
      for (int jt = 0; jt < 4; jt++) {
        bf16x8 bfr = *(const bf16x8*)&sKn[(jt * 16 + lane16) * 136 + ks * 32 + quad * 8];
        aM[jt] = __builtin_amdgcn_mfma_f32_16x16x32_bf16(a, bfr, aM[jt], 0, 0, 0);
      }
    }
    __syncthreads();   // B2

    #pragma unroll
    for (int jt = 0; jt < 4; jt++) {
      int j = jt * 16 + lane16;
      float lj = sl[j];
      #pragma unroll
      for (int r = 0; r < 4; r++) {
        int i = wid * 16 + quad * 4 + r;
        float m = (j <= i) ? expf(sl[i] - lj) * aM[jt][r] : 0.f;
        sM[i * 72 + j] = (short)f2b(m);
      }
    }
    f32x4 aO[8];
    #pragma unroll
    for (int nt = 0; nt < 8; nt++) aO[nt] = f32x4{0.f,0.f,0.f,0.f};
    #pragma unroll
    for (int ks = 0; ks < 4; ks++) {
      bf16x8 a = *(const bf16x8*)&sQ[(wid * 16 + lane16) * 136 + ks * 32 + quad * 8];
      #pragma unroll
      for (int nt = 0; nt < 8; nt++) {
        bf16x8 bfr = *(const bf16x8*)&sS[(nt * 16 + lane16) * 136 + ks * 32 + quad * 8];
        aO[nt] = __builtin_amdgcn_mfma_f32_16x16x32_bf16(a, bfr, aO[nt], 0, 0, 0);
      }
    }
    #pragma unroll
    for (int r = 0; r < 4; r++) {
      float eli = sel[wid * 16 + quad * 4 + r];
      #pragma unroll
      for (int nt = 0; nt < 8; nt++) aO[nt][r] *= eli;
    }
    __syncthreads();   // B3

    #pragma unroll
    for (int ks = 0; ks < 2; ks++) {
      bf16x8 a = *(const bf16x8*)&sM[(wid * 16 + lane16) * 72 + ks * 32 + quad * 8];
      #pragma unroll
      for (int nt = 0; nt < 8; nt++) {
        bf16x8 bfr = *(const bf16x8*)&sDt[(nt * 16 + lane16) * 72 + ks * 32 + quad * 8];
        aO[nt] = __builtin_amdgcn_mfma_f32_16x16x32_bf16(a, bfr, aO[nt], 0, 0, 0);
      }
    }
    #pragma unroll
    for (int r = 0; r < 4; r++) {
      float ss = 0.f;
      #pragma unroll
      for (int nt = 0; nt < 8; nt++) ss += aO[nt][r] * aO[nt][r];
      ss += __shfl_xor(ss, 1, 64);
      ss += __shfl_xor(ss, 2, 64);
      ss += __shfl_xor(ss, 4, 64);
      ss += __shfl_xor(ss, 8, 64);
      float rinv = rsqrtf(ss * (1.f / 128.f) + 1e-6f);
      int i = wid * 16 + quad * 4 + r;
      size_t grow = (size_t)(row0 + i) * NPAD + h * 128;
      #pragma unroll
      for (int nt = 0; nt < 8; nt++) {
        int v = nt * 16 + lane16;
        float zv = b2f((unsigned short)sZ[i * 136 + v]);
        float zg = zv / (1.f + __expf(-zv));
        float y = snw[v] * (aO[nt][r] * rinv) * zg;
        g1out[grow + v] = f2b(y);
      }
    }
    #pragma unroll
    for (int vt2 = 0; vt2 < 2; vt2++) {
      f32x4 aS[8];
      #pragma unroll
      for (int kt = 0; kt < 8; kt++) aS[kt] = f32x4{0.f,0.f,0.f,0.f};
      #pragma unroll
      for (int ks = 0; ks < 2; ks++) {
        bf16x8 a = *(const bf16x8*)&sDt[((wid * 2 + vt2) * 16 + lane16) * 72 + ks * 32 + quad * 8];
        #pragma unroll
        for (int kt = 0; kt < 8; kt++) {
          bf16x8 bfr = *(const bf16x8*)&sK2[(kt * 16 + lane16) * 72 + ks * 32 + quad * 8];
          aS[kt] = __builtin_amdgcn_mfma_f32_16x16x32_bf16(a, bfr, aS[kt], 0, 0, 0);
        }
      }
      #pragma unroll
      for (int kt = 0; kt < 8; kt++)
        #pragma unroll
        for (int r = 0; r < 4; r++)
          Sreg[vt2][kt][r] = elC * Sreg[vt2][kt][r] + aS[kt][r];
    }
    __syncthreads();   // B4
    #pragma unroll
    for (int vt2 = 0; vt2 < 2; vt2++)
      #pragma unroll
      for (int kt = 0; kt < 8; kt++)
        #pragma unroll
        for (int r = 0; r < 4; r++)
          sS[((wid * 2 + vt2) * 16 + quad * 4 + r) * 136 + kt * 16 + lane16] = (short)f2b(Sreg[vt2][kt][r]);
    __syncthreads();   // B5
  }

  float* so = state_out + (size_t)bh * 16384;
  #pragma unroll
  for (int vt2 = 0; vt2 < 2; vt2++)
    #pragma unroll
    for (int kt = 0; kt < 8; kt++)
      #pragma unroll
      for (int r = 0; r < 4; r++)
        so[((wid * 2 + vt2) * 16 + quad * 4 + r) * 128 + kt * 16 + lane16] = Sreg[vt2][kt][r];
}

extern "C" void kernel_launch(void* const* d_in, const int* in_sizes, int n_in,
                              void* d_out, int out_size, void* d_ws, size_t ws_size,
                              hipStream_t stream)
{
  const float* hidden  = (const float*)d_in[0];
  const float* W_qkv   = (const float*)d_in[1];
  const float* W_z     = (const float*)d_in[2];
  const float* W_a     = (const float*)d_in[3];
  const float* W_b     = (const float*)d_in[4];
  const float* conv_w  = (const float*)d_in[5];
  const float* A_log   = (const float*)d_in[6];
  const float* dt_bias = (const float*)d_in[7];
  const float* norm_w  = (const float*)d_in[8];
  const float* W_out   = (const float*)d_in[9];

  char* ws = (char*)d_ws;
  unsigned short* hbf   = (unsigned short*)(ws);                 // [4096][2048] bf16
  unsigned short* Wcat  = (unsigned short*)(ws + 16777216ull);   // [12416][2048] bf16
  unsigned short* Woutb = (unsigned short*)(ws + 67633152ull);   // [2048][4096] bf16
  unsigned short* g1out = (unsigned short*)(ws + 84410368ull);   // [4096][12416] bf16
  unsigned short* qact  = (unsigned short*)(ws + 186122240ull);  // [4096][8192] bf16
  float* g_arr          = (float*)(ws + 253231104ull);           // [4096][32]
  float* beta           = (float*)(ws + 253755392ull);           // [4096][32]
  unsigned short* W_all = (unsigned short*)(ws);                 // aliases hbf (dead after GEMM1)
  unsigned short* U_all = (unsigned short*)(ws + 33554432ull);   // aliases Wcat tail

  float* out0 = (float*)d_out;          // (2,2048,2048) fp32
  float* out1 = out0 + 8388608;         // conv_state (2,8192,4)
  float* out2 = out0 + 8454144;         // state (2,32,128,128)

  cast_kernel<<<8192,  256, 0, stream>>>(hidden, hbf, 2097152);
  cast_kernel<<<16384, 256, 0, stream>>>(W_qkv, Wcat, 4194304);
  cast_kernel<<<8192,  256, 0, stream>>>(W_z,   Wcat + 8192ull  * 2048, 2097152);
  cast_kernel<<<64,    256, 0, stream>>>(W_a,   Wcat + 12288ull * 2048, 16384);
  cast_kernel<<<64,    256, 0, stream>>>(W_b,   Wcat + 12320ull * 2048, 16384);
  cast_kernel<<<8192,  256, 0, stream>>>(W_out, Woutb, 2097152);

  gemm_bt<true><<<dim3(97, 32), 256, 0, stream>>>(hbf, Wcat, g1out, 2048, 2048, 2048, NPAD, NTOT);
  gebeta_kernel<<<512, 256, 0, stream>>>(g1out, A_log, dt_bias, g_arr, beta);
  conv_kernel<<<dim3(4096, 8), 128, 0, stream>>>(g1out, conv_w, qact);
  convstate_kernel<<<256, 256, 0, stream>>>(g1out, out1);

  chunk_prep<<<2048, 256, 0, stream>>>(qact, g_arr, beta, W_all, U_all);
  chunk_scan<<<64, 256, 0, stream>>>(qact, g1out, g_arr, norm_w, W_all, U_all, out2);

  gemm_bt<false><<<dim3(16, 32), 256, 0, stream>>>(g1out, Woutb, out0, 4096, NPAD, 4096, 2048, 2048);
}